// Round 3
// baseline (1637.000 us; speedup 1.0000x reference)
//
#include <hip/hip_runtime.h>
#include <math.h>

// ---------------------------------------------------------------------------
// IsgnBeatMeasEncoder — round 7: kill the vmcnt(0) barrier drain in the LSTM.
// Round-6 post-mortem: 1-barrier redundant-gate restructure bought only 13
// cyc/step (151us -> 150.7us). Revised model: __syncthreads lowers to
// s_waitcnt vmcnt(0) lgkmcnt(0); s_barrier — so the per-step GLOBAL gate
// load (gin is HBM-resident: FETCH_SIZE 327KB ~= gin 256KB + weights) drains
// its ~900cy latency INSIDE every step at the barrier. ~550cy/step exposed.
// Round 7:
//   - raw __builtin_amdgcn_s_barrier() with an lgkmcnt(0)-only wait (gsum is
//     the only cross-wave dependency; LDS counter suffices). Global loads and
//     hid stores stay in flight across the barrier (HK m139 pattern).
//   - 2-step gate prefetch: load for step+2 issued each iter -> ~1600cy of
//     cover for a ~900cy HBM load; its vmcnt wait at use is ~free.
//   - rec32 is single-wave: barrier deleted outright (in-order LDS within a
//     wave), same 2-deep prefetch.
// Everything else unchanged from round 6.
// ---------------------------------------------------------------------------

#define NN    1024
#define EE    10
#define INDIM 78
#define SS    320
#define SECD  128
#define NB    256
#define NM    64
#define CAP   64     // max nonzeros per adjacency column (mean ~10.2)

typedef float v2f __attribute__((ext_vector_type(2)));

__device__ __forceinline__ void pkfma(v2f& a, v2f b, v2f c){
    asm("v_pk_fma_f32 %0, %1, %2, %0" : "+v"(a) : "v"(b), "v"(c));
}

__device__ __forceinline__ float fsig(float x){
    return __builtin_amdgcn_rcpf(1.f + __expf(-x));
}
__device__ __forceinline__ float ftanh(float x){
    // tanh(x) = 1 - 2/(exp(2x)+1); exp overflow -> inf -> rcp -> 0 -> 1 (correct)
    return 1.f - 2.f*__builtin_amdgcn_rcpf(1.f + __expf(2.f*x));
}

// ---------------- note_fc: x0 = tanh(nodes @ W + b); notes_hidden = [0(192) | x0] ----
__global__ void k_note_fc(const float* __restrict__ nodes, const float* __restrict__ W,
                          const float* __restrict__ b, float* __restrict__ nhid){
    int n = blockIdx.x, s = threadIdx.x;           // 128 threads
    __shared__ float xrow[INDIM];
    if (s < INDIM) xrow[s] = nodes[n*INDIM + s];
    __syncthreads();
    float acc = b[s];
    for (int k = 0; k < INDIM; ++k) acc += xrow[k]*W[k*128 + s];
    nhid[n*SS + 192 + s] = ftanh(acc);
    nhid[n*SS + s] = 0.f;
    if (s < 64) nhid[n*SS + 128 + s] = 0.f;
}

// ---------------- CSR build: for each (e, column n) list of source rows m ----------
__global__ void k_csr_build(const float* __restrict__ adj, int* __restrict__ cnt,
                            int* __restrict__ idx){
    int em = blockIdx.x;                   // e*NN + m  (row of adj[e])
    int e = em / NN, m = em % NN;
    const float* row = adj + (size_t)em * NN;
    for (int n = threadIdx.x; n < NN; n += blockDim.x){
        if (row[n] != 0.f){
            int p = atomicAdd(&cnt[e*NN + n], 1);
            if (p < CAP) idx[((size_t)e*NN + n)*CAP + p] = m;
        }
    }
}

// ---------------- act[e,n,f] = sum over column list of x[m,f] ----------------------
__global__ void k_gather_act(const float* __restrict__ x, const int* __restrict__ cnt,
                             const int* __restrict__ idx, float* __restrict__ act){
    int en = blockIdx.x, f = threadIdx.x;  // 320 threads
    int c = cnt[en]; if (c > CAP) c = CAP;
    const int* lst = idx + (size_t)en*CAP;
    float acc = 0.f;
    for (int j = 0; j < c; ++j) acc += x[lst[j]*SS + f];
    act[(size_t)en*SS + f] = acc;
}

// ---------------- gate GEMM: part[z][n][g*128+s] = sum_{e in pair z, f} act*w -------
__global__ __launch_bounds__(256) void k_gate_gemm(const float* __restrict__ act,
        const float* __restrict__ wz, const float* __restrict__ wr,
        const float* __restrict__ wh, float* __restrict__ part){
    __shared__ float A[32*76];     // [kk][row], pad 76
    __shared__ float B[32*132];    // [kk][col], pad 132
    int nt = blockIdx.x, g = blockIdx.y, z = blockIdx.z;
    const float* W = (g==0) ? wz : ((g==1) ? wr : wh);
    int tid = threadIdx.x;
    int tx = tid & 31;             // cols tx*4 .. +3
    int ty = tid >> 5;             // rows ty*8 .. +7
    float acc[8][4];
    #pragma unroll
    for (int i=0;i<8;i++){ acc[i][0]=0.f; acc[i][1]=0.f; acc[i][2]=0.f; acc[i][3]=0.f; }
    for (int eh = 0; eh < 2; ++eh){
        int e = z*2 + eh;
        const float* Ae = act + (size_t)e*NN*SS + (size_t)nt*64*SS;
        const float* We = W   + (size_t)e*SS*SECD;
        for (int kc = 0; kc < SS; kc += 32){
            #pragma unroll
            for (int i=0;i<2;i++){                 // A: 64 rows x 32 k
                int lin4 = tid + i*256;            // 512 float4
                int r  = lin4 >> 3;
                int k4 = (lin4 & 7) << 2;
                float4 v = *(const float4*)(Ae + r*SS + kc + k4);
                A[(k4+0)*76 + r] = v.x; A[(k4+1)*76 + r] = v.y;
                A[(k4+2)*76 + r] = v.z; A[(k4+3)*76 + r] = v.w;
            }
            #pragma unroll
            for (int i=0;i<4;i++){                 // B: 32 k x 128 cols
                int lin4 = tid + i*256;            // 1024 float4
                int kk = lin4 >> 5;
                int c4 = (lin4 & 31) << 2;
                *((float4*)(B + kk*132 + c4)) = *(const float4*)(We + (kc+kk)*SECD + c4);
            }
            __syncthreads();
            #pragma unroll 8
            for (int k=0;k<32;k++){
                float4 a0 = *(const float4*)(A + k*76 + ty*8);
                float4 a1 = *(const float4*)(A + k*76 + ty*8 + 4);
                float4 b0 = *(const float4*)(B + k*132 + tx*4);
                float av[8] = {a0.x,a0.y,a0.z,a0.w,a1.x,a1.y,a1.z,a1.w};
                float bv[4] = {b0.x,b0.y,b0.z,b0.w};
                #pragma unroll
                for (int i=0;i<8;i++)
                    #pragma unroll
                    for (int j=0;j<4;j++) acc[i][j] += av[i]*bv[j];
            }
            __syncthreads();
        }
    }
    float* P = part + ((size_t)z*NN + (size_t)nt*64)*384 + g*SECD;
    #pragma unroll
    for (int i=0;i<8;i++){
        int r = ty*8 + i;
        *(float4*)(P + (size_t)r*384 + tx*4) =
            make_float4(acc[i][0],acc[i][1],acc[i][2],acc[i][3]);
    }
}

// ---------------- GRU update (in place on x's last 128 cols), 4 notes/block --------
__global__ void k_gru(float* __restrict__ x, const float* __restrict__ part,
        const float* __restrict__ uz, const float* __restrict__ ur, const float* __restrict__ uh,
        const float* __restrict__ bz, const float* __restrict__ br, const float* __restrict__ bh){
    int n0 = blockIdx.x*4, s = threadIdx.x;        // 128 threads
    __shared__ float xs[4][SECD], rx[4][SECD];
    #pragma unroll
    for (int j=0;j<4;j++) xs[j][s] = x[(n0+j)*SS + 192 + s];
    __syncthreads();
    float mz[4]={0,0,0,0}, mr[4]={0,0,0,0}, mh[4]={0,0,0,0};
    for (int sp=0; sp<5; sp++){
        const float* Pp = part + ((size_t)sp*NN + n0)*384;
        #pragma unroll
        for (int j=0;j<4;j++){
            mz[j] += Pp[j*384 + s];
            mr[j] += Pp[j*384 + 128 + s];
            mh[j] += Pp[j*384 + 256 + s];
        }
    }
    float dz[4]={0,0,0,0}, dr[4]={0,0,0,0};
    for (int k=0;k<SECD;k++){
        float wz_ = uz[k*SECD + s], wr_ = ur[k*SECD + s];
        #pragma unroll
        for (int j=0;j<4;j++){ float xv = xs[j][k]; dz[j] += xv*wz_; dr[j] += xv*wr_; }
    }
    float zz[4], rr[4];
    #pragma unroll
    for (int j=0;j<4;j++){
        zz[j] = fsig(mz[j] + dz[j] + bz[s]);
        rr[j] = fsig(mr[j] + dr[j] + br[s]);
        rx[j][s] = rr[j]*xs[j][s];
    }
    __syncthreads();
    float dh[4]={0,0,0,0};
    for (int k=0;k<SECD;k++){
        float wh_ = uh[k*SECD + s];
        #pragma unroll
        for (int j=0;j<4;j++) dh[j] += rx[j][k]*wh_;
    }
    #pragma unroll
    for (int j=0;j<4;j++){
        float h = ftanh(mh[j] + dh[j] + bh[s]);
        x[(n0+j)*SS + 192 + s] = (1.f - zz[j])*xs[j][s] + rr[j]*h;
    }
}

// ---------------- nb = relu(nh @ gb_w + gb_b), 8 notes/block -----------------------
__global__ void k_gb(const float* __restrict__ nh, const float* __restrict__ W,
                     const float* __restrict__ b, float* __restrict__ nb){
    int n0 = blockIdx.x*8, s = threadIdx.x;        // 320 threads
    __shared__ float xr[8][SS];
    #pragma unroll
    for (int j=0;j<8;j++) xr[j][s] = nh[(n0+j)*SS + s];
    __syncthreads();
    float acc[8]; float bv = b[s];
    #pragma unroll
    for (int j=0;j<8;j++) acc[j] = bv;
    for (int k=0;k<SS;k++){
        float w = W[k*SS + s];
        #pragma unroll
        for (int j=0;j<8;j++) acc[j] += xr[j][k]*w;
    }
    #pragma unroll
    for (int j=0;j<8;j++) nb[(n0+j)*SS + s] = fmaxf(acc[j], 0.f);
}

// ---------------- cat = [nh[:,192:320] | nh2[:,192:320]] ---------------------------
__global__ void k_build_cat(const float* __restrict__ nh, const float* __restrict__ nh2,
                            float* __restrict__ cat){
    int m = blockIdx.x, s = threadIdx.x;           // 256 threads
    cat[m*256 + s] = (s < 128) ? nh[m*SS + 192 + s] : nh2[m*SS + 64 + s];
}

// ---------------- attention sim: a=tanh(x@W+b); sim[m,h]=dot(a_head, c_head) -------
template<int D, int HD>
__global__ void k_att_sim(const float* __restrict__ x, const float* __restrict__ W,
                          const float* __restrict__ b, const float* __restrict__ c,
                          float* __restrict__ sim){
    int m0 = blockIdx.x*4, s = threadIdx.x;        // D threads
    __shared__ float xr[4][D];
    #pragma unroll
    for (int j=0;j<4;j++) xr[j][s] = x[(m0+j)*D + s];
    __syncthreads();
    float bias = b[s];
    float acc[4] = {bias,bias,bias,bias};
    for (int k=0;k<D;k++){
        float w = W[k*D + s];
        #pragma unroll
        for (int j=0;j<4;j++) acc[j] += xr[j][k]*w;
    }
    float cv = c[s];
    int h = s / HD;
    #pragma unroll
    for (int j=0;j<4;j++){
        float p = ftanh(acc[j])*cv;
        #pragma unroll
        for (int off=HD/2; off>0; off>>=1) p += __shfl_down(p, off);
        if ((s & (HD-1)) == 0) sim[(m0+j)*8 + h] = p;
    }
}

// ---------------- segment softmax (groups of 4 contiguous) + weighted sum ----------
template<int D, int HD>
__global__ void k_att_seg(const float* __restrict__ x, const float* __restrict__ sim,
                          float* __restrict__ out){
    int g = blockIdx.x, s = threadIdx.x;           // D threads
    __shared__ float wgt[4][8];
    if (s < 8){
        float v0 = sim[(g*4+0)*8+s], v1 = sim[(g*4+1)*8+s];
        float v2 = sim[(g*4+2)*8+s], v3 = sim[(g*4+3)*8+s];
        float mx = fmaxf(fmaxf(v0,v1), fmaxf(v2,v3));
        float e0 = __expf(v0-mx), e1 = __expf(v1-mx), e2 = __expf(v2-mx), e3 = __expf(v3-mx);
        float den = e0+e1+e2+e3;
        wgt[0][s]=e0/den; wgt[1][s]=e1/den; wgt[2][s]=e2/den; wgt[3][s]=e3/den;
    }
    __syncthreads();
    int h = s / HD;
    float o = 0.f;
    #pragma unroll
    for (int j=0;j<4;j++) o += x[(g*4+j)*D + s]*wgt[j][h];
    out[g*D + s] = o;
}

// ---------------- LSTM input pre-GEMM: g[t][gi] = b[gi] + wi[gi,:].x[t,:] ----------
template<int TIN, int G4>
__global__ void k_lstm_pre(const float* __restrict__ x,
        const float* __restrict__ wi_f, const float* __restrict__ b_f,
        const float* __restrict__ wi_b, const float* __restrict__ b_b,
        float* __restrict__ gf, float* __restrict__ gbo){
    int t0 = blockIdx.x*4, gi = threadIdx.x;       // G4 threads
    const float* wi = blockIdx.y ? wi_b : wi_f;
    const float* bb = blockIdx.y ? b_b  : b_f;
    float* go       = blockIdx.y ? gbo  : gf;
    __shared__ float xr[4][TIN];
    #pragma unroll
    for (int j=0;j<4;j++)
        for (int k=gi; k<TIN; k+=G4) xr[j][k] = x[(t0+j)*TIN + k];
    __syncthreads();
    float bv = bb[gi];
    float acc[4] = {bv,bv,bv,bv};
    const float* wrow = wi + (size_t)gi*TIN;
    for (int k=0;k<TIN;k++){
        float w = wrow[k];
        #pragma unroll
        for (int j=0;j<4;j++) acc[j] += xr[j][k]*w;
    }
    #pragma unroll
    for (int j=0;j<4;j++) go[(t0+j)*G4 + gi] = acc[j];
}

// ---------------- LSTM recurrence, H=64 T=256: 4 waves, raw barrier, prefetch-2 ----
// Round-6 structure (redundant gate phase, gsum parity double-buffer, every
// wave writes full hs). Round-7 sync: the ONLY per-step wait is
// lgkmcnt(0) + raw s_barrier — the gin global load and hid store stay in
// flight across it. gin prefetched 2 steps ahead (~1600cy cover vs ~900cy
// HBM latency).
#define DOT4(A,W,HV) { A += W.x*HV.x; A += W.y*HV.y; A += W.z*HV.z; A += W.w*HV.w; }
__global__ __launch_bounds__(256)
__attribute__((amdgpu_waves_per_eu(1, 1)))
void k_lstm_rec64(
        const float* __restrict__ gin_f, const float* __restrict__ wh_f,
        const float* __restrict__ gin_b, const float* __restrict__ wh_b,
        float* __restrict__ hid /* [T][128] */){
    const int H = 64, T = 256;
    int dir = blockIdx.x;
    const float* gin = dir ? gin_b : gin_f;
    const float* wh  = dir ? wh_b  : wh_f;
    int gi = threadIdx.x;                  // gate-row in [0, 256)
    int l  = gi & 63;                      // h-index this gate feeds
    const float4* wr = (const float4*)(wh + (size_t)gi*H);
    float4 w0=wr[0], w1=wr[1], w2=wr[2],  w3=wr[3],  w4=wr[4],  w5=wr[5],  w6=wr[6],  w7=wr[7];
    float4 w8=wr[8], w9=wr[9], w10=wr[10],w11=wr[11],w12=wr[12],w13=wr[13],w14=wr[14],w15=wr[15];
    __shared__ __align__(16) float hs[H];
    __shared__ float gsum[2][4*H];
    float c = 0.f;
    if (gi < H) hs[gi] = 0.f;
    __syncthreads();
    const float* gp = gin + gi;
    float gcur = gp[(dir ? (T-1) : 0)*256];
    float gnxt = gp[(dir ? (T-2) : 1)*256];
    for (int step=0; step<T; step++){
        int t = dir ? (T-1-step) : step;
        float gpre = 0.f;
        if (step+2 < T) gpre = gp[(dir ? (T-3-step) : (step+2))*256];
        const float4* hv = (const float4*)hs;      // uniform addr -> LDS broadcast
        float4 h0=hv[0], h1=hv[1], h2=hv[2],  h3=hv[3],  h4=hv[4],  h5=hv[5],  h6=hv[6],  h7=hv[7];
        float4 h8=hv[8], h9=hv[9], h10=hv[10],h11=hv[11],h12=hv[12],h13=hv[13],h14=hv[14],h15=hv[15];
        float a0 = gcur, a1 = 0.f, a2 = 0.f, a3 = 0.f;
        DOT4(a0,w0,h0)   DOT4(a1,w1,h1)   DOT4(a2,w2,h2)   DOT4(a3,w3,h3)
        DOT4(a0,w4,h4)   DOT4(a1,w5,h5)   DOT4(a2,w6,h6)   DOT4(a3,w7,h7)
        DOT4(a0,w8,h8)   DOT4(a1,w9,h9)   DOT4(a2,w10,h10) DOT4(a3,w11,h11)
        DOT4(a0,w12,h12) DOT4(a1,w13,h13) DOT4(a2,w14,h14) DOT4(a3,w15,h15)
        float* gs = gsum[step & 1];
        gs[gi] = (a0+a1) + (a2+a3);
        // LDS-only drain + raw barrier: gin load / hid store stay in flight.
        asm volatile("s_waitcnt lgkmcnt(0)" ::: "memory");
        __builtin_amdgcn_s_barrier();
        __builtin_amdgcn_sched_barrier(0);
        float ig = gs[l], fg = gs[H+l], gg = gs[2*H+l], og = gs[3*H+l];
        c = fsig(fg)*c + fsig(ig)*ftanh(gg);       // all waves: identical update
        float hn = fsig(og)*ftanh(c);
        hs[l] = hn;                                // every wave writes full hs
        if (gi < H) hid[t*2*H + dir*H + gi] = hn;  // one wave publishes
        gcur = gnxt; gnxt = gpre;
    }
}

// ---------------- LSTM recurrence, H=32 T=64: single wave, NO barrier --------------
// Lane gi owns rows {gi, 64+gi}; partner gates via __shfl(x, gi^32). Single
// wave => LDS pipe is in-order: hs write -> next-step hv read needs no
// barrier at all. Gates prefetched 2 steps ahead.
__global__ __launch_bounds__(64)
__attribute__((amdgpu_waves_per_eu(1, 1)))
void k_lstm_rec32(
        const float* __restrict__ gin_f, const float* __restrict__ wh_f,
        const float* __restrict__ gin_b, const float* __restrict__ wh_b,
        float* __restrict__ hid /* [T][64] */){
    const int H = 32, T = 64;
    int dir = blockIdx.x;
    const float* gin = dir ? gin_b : gin_f;
    const float* wh  = dir ? wh_b  : wh_f;
    int gi = threadIdx.x;                  // 0..63
    v2f wA[16], wB[16];
    {
        const v2f* rA = (const v2f*)(wh + (size_t)(     gi)*H);   // rows 0..63:  i|f
        const v2f* rB = (const v2f*)(wh + (size_t)(64 + gi)*H);   // rows 64..127: g|o
        #pragma unroll
        for (int k=0;k<16;k++){ wA[k]=rA[k]; wB[k]=rB[k]; }
    }
    __shared__ __align__(16) float hs[H];
    float c = 0.f;
    if (gi < H) hs[gi] = 0.f;
    __syncthreads();
    const float* gp = gin + gi;
    int ts0 = dir ? (T-1) : 0, ts1 = dir ? (T-2) : 1;
    float g0 = gp[ts0*128], g1 = gp[ts0*128 + 64];
    float n0 = gp[ts1*128], n1 = gp[ts1*128 + 64];
    bool lo = (gi < H);
    for (int step=0; step<T; step++){
        int t = dir ? (T-1-step) : step;
        float p0=0.f, p1=0.f;
        if (step+2 < T){
            int tp = dir ? (T-3-step) : (step+2);
            p0 = gp[tp*128]; p1 = gp[tp*128 + 64];
        }
        v2f aA = {g0, 0.f}, aB = {g1, 0.f};
        const v2f* hv = (const v2f*)hs;
        #pragma unroll
        for (int k=0;k<16;k++){
            v2f h2 = hv[k];
            pkfma(aA, wA[k], h2);
            pkfma(aB, wB[k], h2);
        }
        float sA = aA.x + aA.y;            // lane<32: i ; lane>=32: f
        float sB = aB.x + aB.y;            // lane<32: g ; lane>=32: o
        float pA = __shfl(sA, gi ^ 32);
        float pB = __shfl(sB, gi ^ 32);
        float i_ = lo ? sA : pA;
        float f_ = lo ? pA : sA;
        float g_ = lo ? sB : pB;
        float o_ = lo ? pB : sB;
        c = fsig(f_)*c + fsig(i_)*ftanh(g_);
        float hn = fsig(o_)*ftanh(c);
        if (lo){
            hid[t*2*H + dir*H + gi] = hn;
            hs[gi] = hn;                   // same wave: in-order LDS, no barrier
        }
        g0 = n0; g1 = n1; n0 = p0; n1 = p1;
    }
}

// ---------------- rebuild notes_hidden = [beat_span | meas_span | nh_sec] ----------
__global__ void k_spans(float* __restrict__ nhid, const float* __restrict__ bh,
                        const float* __restrict__ mh, const float* __restrict__ nh,
                        const int* __restrict__ bn, const int* __restrict__ mn){
    int n = blockIdx.x, s = threadIdx.x;           // 320 threads
    float v;
    if (s < 128)      v = bh[bn[n]*128 + s];
    else if (s < 192) v = mh[mn[n]*64 + (s-128)];
    else              v = nh[n*SS + s];
    nhid[n*SS + s] = v;
}

// ---------------- final output = [notes_hidden(320) | nh2_sec(128)] ----------------
__global__ void k_final(const float* __restrict__ nhid, const float* __restrict__ nh2,
                        float* __restrict__ out){
    int n = blockIdx.x, s = threadIdx.x;           // 448 threads
    out[n*448 + s] = (s < 320) ? nhid[n*SS + s] : nh2[n*SS + 192 + (s-320)];
}

// ===========================================================================
extern "C" void kernel_launch(void* const* d_in, const int* in_sizes, int n_in,
                              void* d_out, int out_size, void* d_ws, size_t ws_size,
                              hipStream_t stream) {
    const float* nodes    = (const float*)d_in[0];
    const float* adj      = (const float*)d_in[1];
    const int*   bn       = (const int*)  d_in[2];
    const int*   mn       = (const int*)  d_in[3];
    const float* fc_w     = (const float*)d_in[6];
    const float* fc_b     = (const float*)d_in[7];
    const float* g_wz[2]  = {(const float*)d_in[8],  (const float*)d_in[17]};
    const float* g_wr[2]  = {(const float*)d_in[9],  (const float*)d_in[18]};
    const float* g_wh[2]  = {(const float*)d_in[10], (const float*)d_in[19]};
    const float* g_uz[2]  = {(const float*)d_in[11], (const float*)d_in[20]};
    const float* g_ur[2]  = {(const float*)d_in[12], (const float*)d_in[21]};
    const float* g_uh[2]  = {(const float*)d_in[13], (const float*)d_in[22]};
    const float* g_bz[2]  = {(const float*)d_in[14], (const float*)d_in[23]};
    const float* g_br[2]  = {(const float*)d_in[15], (const float*)d_in[24]};
    const float* g_bh[2]  = {(const float*)d_in[16], (const float*)d_in[25]};
    const float* gb_w     = (const float*)d_in[26];
    const float* gb_b     = (const float*)d_in[27];
    const float* batt_w   = (const float*)d_in[28];
    const float* batt_b   = (const float*)d_in[29];
    const float* batt_c   = (const float*)d_in[30];
    const float* matt_w   = (const float*)d_in[31];
    const float* matt_b   = (const float*)d_in[32];
    const float* matt_c   = (const float*)d_in[33];
    const float* bwi_f    = (const float*)d_in[34];
    const float* bwh_f    = (const float*)d_in[35];
    const float* bb_f     = (const float*)d_in[36];
    const float* bwi_b    = (const float*)d_in[37];
    const float* bwh_b    = (const float*)d_in[38];
    const float* bb_b     = (const float*)d_in[39];
    const float* mwi_f    = (const float*)d_in[40];
    const float* mwh_f    = (const float*)d_in[41];
    const float* mb_f     = (const float*)d_in[42];
    const float* mwi_b    = (const float*)d_in[43];
    const float* mwh_b    = (const float*)d_in[44];
    const float* mb_b     = (const float*)d_in[45];
    float* out = (float*)d_out;

    // --- workspace layout (floats; total ~31 MB) ---
    float* W_   = (float*)d_ws;
    float* nhid = W_;                       // 1024*320
    float* nh   = nhid + 327680;            // 1024*320
    float* nh2  = nh   + 327680;            // 1024*320
    float* nb   = nh2  + 327680;            // 1024*320
    float* act  = nb   + 327680;            // 10*1024*320
    float* part = act  + 3276800;           // 5*1024*384
    float* cat  = part + 1966080;           // 1024*256
    float* sim  = cat  + 262144;            // 1024*8
    float* beat_nodes = sim + 8192;         // 256*256
    float* bgf  = beat_nodes + 65536;       // 256*256
    float* bgb  = bgf  + 65536;             // 256*256
    float* beat_hidden = bgb + 65536;       // 256*128
    float* msim = beat_hidden + 32768;      // 256*8
    float* meas_nodes = msim + 2048;        // 64*128
    float* mgf  = meas_nodes + 8192;        // 64*128
    float* mgb  = mgf  + 8192;              // 64*128
    float* meas_hidden = mgb + 8192;        // 64*64
    int*   cnt  = (int*)(meas_hidden + 4096);  // 10*1024
    int*   idx  = cnt + 10240;                  // 10*1024*64

    hipMemsetAsync(cnt, 0, EE*NN*sizeof(int), stream);
    k_csr_build<<<EE*NN, 256, 0, stream>>>(adj, cnt, idx);
    k_note_fc<<<NN, 128, 0, stream>>>(nodes, fc_w, fc_b, nhid);

    for (int si = 0; si < 2; ++si){
        hipMemcpyAsync(nh, nhid, (size_t)NN*SS*sizeof(float), hipMemcpyDeviceToDevice, stream);
        for (int it = 0; it < 2; ++it){
            k_gather_act<<<EE*NN, SS, 0, stream>>>(nh, cnt, idx, act);
            k_gate_gemm<<<dim3(16,3,5), 256, 0, stream>>>(act, g_wz[0], g_wr[0], g_wh[0], part);
            k_gru<<<NN/4, 128, 0, stream>>>(nh, part, g_uz[0], g_ur[0], g_uh[0],
                                            g_bz[0], g_br[0], g_bh[0]);
        }
        k_gb<<<NN/8, SS, 0, stream>>>(nh, gb_w, gb_b, nb);
        hipMemcpyAsync(nh2, nb, (size_t)NN*SS*sizeof(float), hipMemcpyDeviceToDevice, stream);
        for (int it = 0; it < 2; ++it){
            k_gather_act<<<EE*NN, SS, 0, stream>>>(nh2, cnt, idx, act);
            k_gate_gemm<<<dim3(16,3,5), 256, 0, stream>>>(act, g_wz[1], g_wr[1], g_wh[1], part);
            k_gru<<<NN/4, 128, 0, stream>>>(nh2, part, g_uz[1], g_ur[1], g_uh[1],
                                            g_bz[1], g_br[1], g_bh[1]);
        }
        k_build_cat<<<NN, 256, 0, stream>>>(nh, nh2, cat);
        k_att_sim<256,32><<<NN/4, 256, 0, stream>>>(cat, batt_w, batt_b, batt_c, sim);
        k_att_seg<256,32><<<NB, 256, 0, stream>>>(cat, sim, beat_nodes);
        k_lstm_pre<256,256><<<dim3(NB/4,2), 256, 0, stream>>>(beat_nodes, bwi_f, bb_f,
                                                              bwi_b, bb_b, bgf, bgb);
        k_lstm_rec64<<<2, 256, 0, stream>>>(bgf, bwh_f, bgb, bwh_b, beat_hidden);
        k_att_sim<128,16><<<NB/4, 128, 0, stream>>>(beat_hidden, matt_w, matt_b, matt_c, msim);
        k_att_seg<128,16><<<NM, 128, 0, stream>>>(beat_hidden, msim, meas_nodes);
        k_lstm_pre<128,128><<<dim3(NM/4,2), 128, 0, stream>>>(meas_nodes, mwi_f, mb_f,
                                                              mwi_b, mb_b, mgf, mgb);
        k_lstm_rec32<<<2, 64, 0, stream>>>(mgf, mwh_f, mgb, mwh_b, meas_hidden);
        k_spans<<<NN, SS, 0, stream>>>(nhid, beat_hidden, meas_hidden, nh, bn, mn);
    }
    k_final<<<NN, 448, 0, stream>>>(nhid, nh2, out);
}

// Round 4
// 1595.478 us; speedup vs baseline: 1.0260x; 1.0260x over previous
//
#include <hip/hip_runtime.h>
#include <math.h>

// ---------------------------------------------------------------------------
// IsgnBeatMeasEncoder — round 8: fewer dispatches, fused attention, revert rec64.
// Round-7 post-mortem: raw-barrier + prefetch-2 HURT rec64 (150.7 -> 165.4us).
// Three sync-structure edits in a row were null-to-negative around a ~1400
// "cycle" plateau; model says the step floor is ~850 cy -> the chip is almost
// certainly running at reduced clock (2 CUs busy, tiny bursty kernels).
// => stop micro-tuning rec64 (revert to round-6 best); attack total serial
// work + dispatch count instead:
//   - k_batt_fused: build_cat + att_sim + att_seg + lstm_pre(beat) in ONE
//     kernel (beat_nodes/cat/sim never touch HBM).
//   - k_matt_fused: same for measure side.
//   - nhid buffer + all 4 hipMemcpyAsync eliminated: note_fc writes nh,
//     spans(si=0) rebuilds nh in place, spans_out(si=1) writes final output
//     directly (absorbs k_final). k_gb writes nh2 directly (nb gone).
//   - rec32 keeps round-7 barrier-free single-wave form (verified passing).
// ~46 -> ~33 dispatches per graph.
// ---------------------------------------------------------------------------

#define NN    1024
#define EE    10
#define INDIM 78
#define SS    320
#define SECD  128
#define NB    256
#define NM    64
#define CAP   64     // max nonzeros per adjacency column (mean ~10.2)

typedef float v2f __attribute__((ext_vector_type(2)));

__device__ __forceinline__ void pkfma(v2f& a, v2f b, v2f c){
    asm("v_pk_fma_f32 %0, %1, %2, %0" : "+v"(a) : "v"(b), "v"(c));
}

__device__ __forceinline__ float fsig(float x){
    return __builtin_amdgcn_rcpf(1.f + __expf(-x));
}
__device__ __forceinline__ float ftanh(float x){
    // tanh(x) = 1 - 2/(exp(2x)+1); exp overflow -> inf -> rcp -> 0 -> 1 (correct)
    return 1.f - 2.f*__builtin_amdgcn_rcpf(1.f + __expf(2.f*x));
}

// ---------------- note_fc: x0 = tanh(nodes @ W + b); nh = [0(192) | x0] ------------
__global__ void k_note_fc(const float* __restrict__ nodes, const float* __restrict__ W,
                          const float* __restrict__ b, float* __restrict__ nh){
    int n = blockIdx.x, s = threadIdx.x;           // 128 threads
    __shared__ float xrow[INDIM];
    if (s < INDIM) xrow[s] = nodes[n*INDIM + s];
    __syncthreads();
    float acc = b[s];
    for (int k = 0; k < INDIM; ++k) acc += xrow[k]*W[k*128 + s];
    nh[n*SS + 192 + s] = ftanh(acc);
    nh[n*SS + s] = 0.f;
    if (s < 64) nh[n*SS + 128 + s] = 0.f;
}

// ---------------- CSR build: for each (e, column n) list of source rows m ----------
__global__ void k_csr_build(const float* __restrict__ adj, int* __restrict__ cnt,
                            int* __restrict__ idx){
    int em = blockIdx.x;                   // e*NN + m  (row of adj[e])
    int e = em / NN, m = em % NN;
    const float* row = adj + (size_t)em * NN;
    for (int n = threadIdx.x; n < NN; n += blockDim.x){
        if (row[n] != 0.f){
            int p = atomicAdd(&cnt[e*NN + n], 1);
            if (p < CAP) idx[((size_t)e*NN + n)*CAP + p] = m;
        }
    }
}

// ---------------- act[e,n,f] = sum over column list of x[m,f] ----------------------
__global__ void k_gather_act(const float* __restrict__ x, const int* __restrict__ cnt,
                             const int* __restrict__ idx, float* __restrict__ act){
    int en = blockIdx.x, f = threadIdx.x;  // 320 threads
    int c = cnt[en]; if (c > CAP) c = CAP;
    const int* lst = idx + (size_t)en*CAP;
    float acc = 0.f;
    for (int j = 0; j < c; ++j) acc += x[lst[j]*SS + f];
    act[(size_t)en*SS + f] = acc;
}

// ---------------- gate GEMM: part[z][n][g*128+s] = sum_{e in pair z, f} act*w -------
__global__ __launch_bounds__(256) void k_gate_gemm(const float* __restrict__ act,
        const float* __restrict__ wz, const float* __restrict__ wr,
        const float* __restrict__ wh, float* __restrict__ part){
    __shared__ float A[32*76];     // [kk][row], pad 76
    __shared__ float B[32*132];    // [kk][col], pad 132
    int nt = blockIdx.x, g = blockIdx.y, z = blockIdx.z;
    const float* W = (g==0) ? wz : ((g==1) ? wr : wh);
    int tid = threadIdx.x;
    int tx = tid & 31;             // cols tx*4 .. +3
    int ty = tid >> 5;             // rows ty*8 .. +7
    float acc[8][4];
    #pragma unroll
    for (int i=0;i<8;i++){ acc[i][0]=0.f; acc[i][1]=0.f; acc[i][2]=0.f; acc[i][3]=0.f; }
    for (int eh = 0; eh < 2; ++eh){
        int e = z*2 + eh;
        const float* Ae = act + (size_t)e*NN*SS + (size_t)nt*64*SS;
        const float* We = W   + (size_t)e*SS*SECD;
        for (int kc = 0; kc < SS; kc += 32){
            #pragma unroll
            for (int i=0;i<2;i++){                 // A: 64 rows x 32 k
                int lin4 = tid + i*256;            // 512 float4
                int r  = lin4 >> 3;
                int k4 = (lin4 & 7) << 2;
                float4 v = *(const float4*)(Ae + r*SS + kc + k4);
                A[(k4+0)*76 + r] = v.x; A[(k4+1)*76 + r] = v.y;
                A[(k4+2)*76 + r] = v.z; A[(k4+3)*76 + r] = v.w;
            }
            #pragma unroll
            for (int i=0;i<4;i++){                 // B: 32 k x 128 cols
                int lin4 = tid + i*256;            // 1024 float4
                int kk = lin4 >> 5;
                int c4 = (lin4 & 31) << 2;
                *((float4*)(B + kk*132 + c4)) = *(const float4*)(We + (kc+kk)*SECD + c4);
            }
            __syncthreads();
            #pragma unroll 8
            for (int k=0;k<32;k++){
                float4 a0 = *(const float4*)(A + k*76 + ty*8);
                float4 a1 = *(const float4*)(A + k*76 + ty*8 + 4);
                float4 b0 = *(const float4*)(B + k*132 + tx*4);
                float av[8] = {a0.x,a0.y,a0.z,a0.w,a1.x,a1.y,a1.z,a1.w};
                float bv[4] = {b0.x,b0.y,b0.z,b0.w};
                #pragma unroll
                for (int i=0;i<8;i++)
                    #pragma unroll
                    for (int j=0;j<4;j++) acc[i][j] += av[i]*bv[j];
            }
            __syncthreads();
        }
    }
    float* P = part + ((size_t)z*NN + (size_t)nt*64)*384 + g*SECD;
    #pragma unroll
    for (int i=0;i<8;i++){
        int r = ty*8 + i;
        *(float4*)(P + (size_t)r*384 + tx*4) =
            make_float4(acc[i][0],acc[i][1],acc[i][2],acc[i][3]);
    }
}

// ---------------- GRU update (in place on x's last 128 cols), 4 notes/block --------
__global__ void k_gru(float* __restrict__ x, const float* __restrict__ part,
        const float* __restrict__ uz, const float* __restrict__ ur, const float* __restrict__ uh,
        const float* __restrict__ bz, const float* __restrict__ br, const float* __restrict__ bh){
    int n0 = blockIdx.x*4, s = threadIdx.x;        // 128 threads
    __shared__ float xs[4][SECD], rx[4][SECD];
    #pragma unroll
    for (int j=0;j<4;j++) xs[j][s] = x[(n0+j)*SS + 192 + s];
    __syncthreads();
    float mz[4]={0,0,0,0}, mr[4]={0,0,0,0}, mh[4]={0,0,0,0};
    for (int sp=0; sp<5; sp++){
        const float* Pp = part + ((size_t)sp*NN + n0)*384;
        #pragma unroll
        for (int j=0;j<4;j++){
            mz[j] += Pp[j*384 + s];
            mr[j] += Pp[j*384 + 128 + s];
            mh[j] += Pp[j*384 + 256 + s];
        }
    }
    float dz[4]={0,0,0,0}, dr[4]={0,0,0,0};
    for (int k=0;k<SECD;k++){
        float wz_ = uz[k*SECD + s], wr_ = ur[k*SECD + s];
        #pragma unroll
        for (int j=0;j<4;j++){ float xv = xs[j][k]; dz[j] += xv*wz_; dr[j] += xv*wr_; }
    }
    float zz[4], rr[4];
    #pragma unroll
    for (int j=0;j<4;j++){
        zz[j] = fsig(mz[j] + dz[j] + bz[s]);
        rr[j] = fsig(mr[j] + dr[j] + br[s]);
        rx[j][s] = rr[j]*xs[j][s];
    }
    __syncthreads();
    float dh[4]={0,0,0,0};
    for (int k=0;k<SECD;k++){
        float wh_ = uh[k*SECD + s];
        #pragma unroll
        for (int j=0;j<4;j++) dh[j] += rx[j][k]*wh_;
    }
    #pragma unroll
    for (int j=0;j<4;j++){
        float h = ftanh(mh[j] + dh[j] + bh[s]);
        x[(n0+j)*SS + 192 + s] = (1.f - zz[j])*xs[j][s] + rr[j]*h;
    }
}

// ---------------- nb = relu(nh @ gb_w + gb_b) written straight into nh2 ------------
__global__ void k_gb(const float* __restrict__ nh, const float* __restrict__ W,
                     const float* __restrict__ b, float* __restrict__ nb){
    int n0 = blockIdx.x*8, s = threadIdx.x;        // 320 threads
    __shared__ float xr[8][SS];
    #pragma unroll
    for (int j=0;j<8;j++) xr[j][s] = nh[(n0+j)*SS + s];
    __syncthreads();
    float acc[8]; float bv = b[s];
    #pragma unroll
    for (int j=0;j<8;j++) acc[j] = bv;
    for (int k=0;k<SS;k++){
        float w = W[k*SS + s];
        #pragma unroll
        for (int j=0;j<8;j++) acc[j] += xr[j][k]*w;
    }
    #pragma unroll
    for (int j=0;j<8;j++) nb[(n0+j)*SS + s] = fmaxf(acc[j], 0.f);
}

// ---------------- FUSED beat attention + lstm_pre ----------------------------------
// Per block g: rows m=4g..4g+3. cat built inline from nh/nh2; sim + segment
// softmax + weighted sum in-block; then both direction input-GEMVs.
// cat/sim/beat_nodes never touch HBM.
__global__ __launch_bounds__(256) void k_batt_fused(
        const float* __restrict__ nh, const float* __restrict__ nh2,
        const float* __restrict__ W, const float* __restrict__ b,
        const float* __restrict__ cvec,
        const float* __restrict__ wi_f, const float* __restrict__ b_f,
        const float* __restrict__ wi_b, const float* __restrict__ b_b,
        float* __restrict__ gf, float* __restrict__ gbo){
    int g = blockIdx.x, s = threadIdx.x;           // 256 threads
    __shared__ float xr[4][256];
    __shared__ float simw[4][8];
    __shared__ float wgt[4][8];
    __shared__ float bnode[256];
    #pragma unroll
    for (int j=0;j<4;j++){
        int m = g*4 + j;
        xr[j][s] = (s < 128) ? nh[m*SS + 192 + s] : nh2[m*SS + 64 + s];
    }
    __syncthreads();
    float bias = b[s];
    float acc[4] = {bias,bias,bias,bias};
    for (int k=0;k<256;k++){
        float w = W[k*256 + s];
        #pragma unroll
        for (int j=0;j<4;j++) acc[j] += xr[j][k]*w;
    }
    float cv = cvec[s];
    int h = s >> 5;                                // head (HD=32)
    #pragma unroll
    for (int j=0;j<4;j++){
        float p = ftanh(acc[j])*cv;
        #pragma unroll
        for (int off=16; off>0; off>>=1) p += __shfl_down(p, off);
        if ((s & 31) == 0) simw[j][h] = p;
    }
    __syncthreads();
    if (s < 8){
        float v0=simw[0][s], v1=simw[1][s], v2=simw[2][s], v3=simw[3][s];
        float mx = fmaxf(fmaxf(v0,v1), fmaxf(v2,v3));
        float e0=__expf(v0-mx), e1=__expf(v1-mx), e2=__expf(v2-mx), e3=__expf(v3-mx);
        float den = e0+e1+e2+e3;
        wgt[0][s]=e0/den; wgt[1][s]=e1/den; wgt[2][s]=e2/den; wgt[3][s]=e3/den;
    }
    __syncthreads();
    float o = 0.f;
    #pragma unroll
    for (int j=0;j<4;j++) o += xr[j][s]*wgt[j][h];
    bnode[s] = o;
    __syncthreads();
    float af = b_f[s], ab = b_b[s];
    const float* wf = wi_f + (size_t)s*256;
    const float* wb = wi_b + (size_t)s*256;
    for (int k=0;k<256;k++){
        float x = bnode[k];
        af += wf[k]*x;
        ab += wb[k]*x;
    }
    gf [g*256 + s] = af;
    gbo[g*256 + s] = ab;
}

// ---------------- FUSED measure attention + lstm_pre -------------------------------
__global__ __launch_bounds__(128) void k_matt_fused(
        const float* __restrict__ bh,   // beat_hidden [256][128]
        const float* __restrict__ W, const float* __restrict__ b,
        const float* __restrict__ cvec,
        const float* __restrict__ wi_f, const float* __restrict__ b_f,
        const float* __restrict__ wi_b, const float* __restrict__ b_b,
        float* __restrict__ gf, float* __restrict__ gbo){
    int g = blockIdx.x, s = threadIdx.x;           // 128 threads
    __shared__ float xr[4][128];
    __shared__ float simw[4][8];
    __shared__ float wgt[4][8];
    __shared__ float mnode[128];
    #pragma unroll
    for (int j=0;j<4;j++) xr[j][s] = bh[(g*4+j)*128 + s];
    __syncthreads();
    float bias = b[s];
    float acc[4] = {bias,bias,bias,bias};
    for (int k=0;k<128;k++){
        float w = W[k*128 + s];
        #pragma unroll
        for (int j=0;j<4;j++) acc[j] += xr[j][k]*w;
    }
    float cv = cvec[s];
    int h = s >> 4;                                // head (HD=16)
    #pragma unroll
    for (int j=0;j<4;j++){
        float p = ftanh(acc[j])*cv;
        #pragma unroll
        for (int off=8; off>0; off>>=1) p += __shfl_down(p, off);
        if ((s & 15) == 0) simw[j][h] = p;
    }
    __syncthreads();
    if (s < 8){
        float v0=simw[0][s], v1=simw[1][s], v2=simw[2][s], v3=simw[3][s];
        float mx = fmaxf(fmaxf(v0,v1), fmaxf(v2,v3));
        float e0=__expf(v0-mx), e1=__expf(v1-mx), e2=__expf(v2-mx), e3=__expf(v3-mx);
        float den = e0+e1+e2+e3;
        wgt[0][s]=e0/den; wgt[1][s]=e1/den; wgt[2][s]=e2/den; wgt[3][s]=e3/den;
    }
    __syncthreads();
    float o = 0.f;
    #pragma unroll
    for (int j=0;j<4;j++) o += xr[j][s]*wgt[j][h];
    mnode[s] = o;
    __syncthreads();
    float af = b_f[s], ab = b_b[s];
    const float* wf = wi_f + (size_t)s*128;
    const float* wb = wi_b + (size_t)s*128;
    for (int k=0;k<128;k++){
        float x = mnode[k];
        af += wf[k]*x;
        ab += wb[k]*x;
    }
    gf [g*128 + s] = af;
    gbo[g*128 + s] = ab;
}

// ---------------- LSTM recurrence, H=64 T=256: round-6 form (best measured) --------
// 4 waves, redundant gate phase, gsum parity double-buffer, 1 barrier/step.
#define DOT4(A,W,HV) { A += W.x*HV.x; A += W.y*HV.y; A += W.z*HV.z; A += W.w*HV.w; }
__global__ __launch_bounds__(256)
__attribute__((amdgpu_waves_per_eu(1, 1)))
void k_lstm_rec64(
        const float* __restrict__ gin_f, const float* __restrict__ wh_f,
        const float* __restrict__ gin_b, const float* __restrict__ wh_b,
        float* __restrict__ hid /* [T][128] */){
    const int H = 64, T = 256;
    int dir = blockIdx.x;
    const float* gin = dir ? gin_b : gin_f;
    const float* wh  = dir ? wh_b  : wh_f;
    int gi = threadIdx.x;                  // gate-row in [0, 256)
    int l  = gi & 63;                      // h-index this gate feeds
    const float4* wr = (const float4*)(wh + (size_t)gi*H);
    float4 w0=wr[0], w1=wr[1], w2=wr[2],  w3=wr[3],  w4=wr[4],  w5=wr[5],  w6=wr[6],  w7=wr[7];
    float4 w8=wr[8], w9=wr[9], w10=wr[10],w11=wr[11],w12=wr[12],w13=wr[13],w14=wr[14],w15=wr[15];
    __shared__ __align__(16) float hs[H];
    __shared__ float gsum[2][4*H];
    float c = 0.f;
    if (gi < H) hs[gi] = 0.f;
    __syncthreads();
    float gcur = gin[(dir ? (T-1) : 0)*4*H + gi];
    for (int step=0; step<T; step++){
        int t = dir ? (T-1-step) : step;
        float gnext = 0.f;
        if (step+1 < T) gnext = gin[(dir ? (T-2-step) : (step+1))*4*H + gi];
        const float4* hv = (const float4*)hs;      // uniform addr -> LDS broadcast
        float4 h0=hv[0], h1=hv[1], h2=hv[2],  h3=hv[3],  h4=hv[4],  h5=hv[5],  h6=hv[6],  h7=hv[7];
        float4 h8=hv[8], h9=hv[9], h10=hv[10],h11=hv[11],h12=hv[12],h13=hv[13],h14=hv[14],h15=hv[15];
        float a0 = gcur, a1 = 0.f, a2 = 0.f, a3 = 0.f;
        DOT4(a0,w0,h0)   DOT4(a1,w1,h1)   DOT4(a2,w2,h2)   DOT4(a3,w3,h3)
        DOT4(a0,w4,h4)   DOT4(a1,w5,h5)   DOT4(a2,w6,h6)   DOT4(a3,w7,h7)
        DOT4(a0,w8,h8)   DOT4(a1,w9,h9)   DOT4(a2,w10,h10) DOT4(a3,w11,h11)
        DOT4(a0,w12,h12) DOT4(a1,w13,h13) DOT4(a2,w14,h14) DOT4(a3,w15,h15)
        float* gs = gsum[step & 1];
        gs[gi] = (a0+a1) + (a2+a3);
        __syncthreads();                           // the ONLY barrier per step
        float ig = gs[l], fg = gs[H+l], gg = gs[2*H+l], og = gs[3*H+l];
        c = fsig(fg)*c + fsig(ig)*ftanh(gg);       // all waves: identical update
        float hn = fsig(og)*ftanh(c);
        hs[l] = hn;                                // every wave writes full hs
        if (gi < H) hid[t*2*H + dir*H + gi] = hn;  // one wave publishes
        gcur = gnext;
    }
}

// ---------------- LSTM recurrence, H=32 T=64: single wave, NO barrier --------------
// (round-7 form, verified) Lane gi owns rows {gi, 64+gi}; partner gates via
// __shfl(x, gi^32). Single wave => LDS in-order, no barrier. Prefetch-2.
__global__ __launch_bounds__(64)
__attribute__((amdgpu_waves_per_eu(1, 1)))
void k_lstm_rec32(
        const float* __restrict__ gin_f, const float* __restrict__ wh_f,
        const float* __restrict__ gin_b, const float* __restrict__ wh_b,
        float* __restrict__ hid /* [T][64] */){
    const int H = 32, T = 64;
    int dir = blockIdx.x;
    const float* gin = dir ? gin_b : gin_f;
    const float* wh  = dir ? wh_b  : wh_f;
    int gi = threadIdx.x;                  // 0..63
    v2f wA[16], wB[16];
    {
        const v2f* rA = (const v2f*)(wh + (size_t)(     gi)*H);   // rows 0..63:  i|f
        const v2f* rB = (const v2f*)(wh + (size_t)(64 + gi)*H);   // rows 64..127: g|o
        #pragma unroll
        for (int k=0;k<16;k++){ wA[k]=rA[k]; wB[k]=rB[k]; }
    }
    __shared__ __align__(16) float hs[H];
    float c = 0.f;
    if (gi < H) hs[gi] = 0.f;
    __syncthreads();
    const float* gp = gin + gi;
    int ts0 = dir ? (T-1) : 0, ts1 = dir ? (T-2) : 1;
    float g0 = gp[ts0*128], g1 = gp[ts0*128 + 64];
    float n0 = gp[ts1*128], n1 = gp[ts1*128 + 64];
    bool lo = (gi < H);
    for (int step=0; step<T; step++){
        int t = dir ? (T-1-step) : step;
        float p0=0.f, p1=0.f;
        if (step+2 < T){
            int tp = dir ? (T-3-step) : (step+2);
            p0 = gp[tp*128]; p1 = gp[tp*128 + 64];
        }
        v2f aA = {g0, 0.f}, aB = {g1, 0.f};
        const v2f* hv = (const v2f*)hs;
        #pragma unroll
        for (int k=0;k<16;k++){
            v2f h2 = hv[k];
            pkfma(aA, wA[k], h2);
            pkfma(aB, wB[k], h2);
        }
        float sA = aA.x + aA.y;            // lane<32: i ; lane>=32: f
        float sB = aB.x + aB.y;            // lane<32: g ; lane>=32: o
        float pA = __shfl(sA, gi ^ 32);
        float pB = __shfl(sB, gi ^ 32);
        float i_ = lo ? sA : pA;
        float f_ = lo ? pA : sA;
        float g_ = lo ? sB : pB;
        float o_ = lo ? pB : sB;
        c = fsig(f_)*c + fsig(i_)*ftanh(g_);
        float hn = fsig(o_)*ftanh(c);
        if (lo){
            hid[t*2*H + dir*H + gi] = hn;
            hs[gi] = hn;                   // same wave: in-order LDS, no barrier
        }
        g0 = n0; g1 = n1; n0 = p0; n1 = p1;
    }
}

// ---------------- si=0: rebuild nh in place = [beat_span | meas_span | nh_sec] -----
__global__ void k_spans(float* __restrict__ nh, const float* __restrict__ bh,
                        const float* __restrict__ mh,
                        const int* __restrict__ bn, const int* __restrict__ mn){
    int n = blockIdx.x, s = threadIdx.x;           // 320 threads
    float v;
    if (s < 128)      v = bh[bn[n]*128 + s];
    else if (s < 192) v = mh[mn[n]*64 + (s-128)];
    else              v = nh[n*SS + s];            // own-thread read-then-write: safe
    nh[n*SS + s] = v;
}

// ---------------- si=1: spans + final output fused ---------------------------------
__global__ void k_spans_out(const float* __restrict__ bh, const float* __restrict__ mh,
                            const float* __restrict__ nh, const float* __restrict__ nh2,
                            const int* __restrict__ bn, const int* __restrict__ mn,
                            float* __restrict__ out){
    int n = blockIdx.x, s = threadIdx.x;           // 448 threads
    float v;
    if (s < 128)      v = bh[bn[n]*128 + s];
    else if (s < 192) v = mh[mn[n]*64 + (s-128)];
    else if (s < 320) v = nh[n*SS + s];
    else              v = nh2[n*SS + 192 + (s-320)];
    out[n*448 + s] = v;
}

// ===========================================================================
extern "C" void kernel_launch(void* const* d_in, const int* in_sizes, int n_in,
                              void* d_out, int out_size, void* d_ws, size_t ws_size,
                              hipStream_t stream) {
    const float* nodes    = (const float*)d_in[0];
    const float* adj      = (const float*)d_in[1];
    const int*   bn       = (const int*)  d_in[2];
    const int*   mn       = (const int*)  d_in[3];
    const float* fc_w     = (const float*)d_in[6];
    const float* fc_b     = (const float*)d_in[7];
    const float* g_wz[2]  = {(const float*)d_in[8],  (const float*)d_in[17]};
    const float* g_wr[2]  = {(const float*)d_in[9],  (const float*)d_in[18]};
    const float* g_wh[2]  = {(const float*)d_in[10], (const float*)d_in[19]};
    const float* g_uz[2]  = {(const float*)d_in[11], (const float*)d_in[20]};
    const float* g_ur[2]  = {(const float*)d_in[12], (const float*)d_in[21]};
    const float* g_uh[2]  = {(const float*)d_in[13], (const float*)d_in[22]};
    const float* g_bz[2]  = {(const float*)d_in[14], (const float*)d_in[23]};
    const float* g_br[2]  = {(const float*)d_in[15], (const float*)d_in[24]};
    const float* g_bh[2]  = {(const float*)d_in[16], (const float*)d_in[25]};
    const float* gb_w     = (const float*)d_in[26];
    const float* gb_b     = (const float*)d_in[27];
    const float* batt_w   = (const float*)d_in[28];
    const float* batt_b   = (const float*)d_in[29];
    const float* batt_c   = (const float*)d_in[30];
    const float* matt_w   = (const float*)d_in[31];
    const float* matt_b   = (const float*)d_in[32];
    const float* matt_c   = (const float*)d_in[33];
    const float* bwi_f    = (const float*)d_in[34];
    const float* bwh_f    = (const float*)d_in[35];
    const float* bb_f     = (const float*)d_in[36];
    const float* bwi_b    = (const float*)d_in[37];
    const float* bwh_b    = (const float*)d_in[38];
    const float* bb_b     = (const float*)d_in[39];
    const float* mwi_f    = (const float*)d_in[40];
    const float* mwh_f    = (const float*)d_in[41];
    const float* mb_f     = (const float*)d_in[42];
    const float* mwi_b    = (const float*)d_in[43];
    const float* mwh_b    = (const float*)d_in[44];
    const float* mb_b     = (const float*)d_in[45];
    float* out = (float*)d_out;

    // --- workspace layout (floats; ~27 MB) ---
    float* W_   = (float*)d_ws;
    float* nh   = W_;                       // 1024*320
    float* nh2  = nh   + 327680;            // 1024*320
    float* act  = nh2  + 327680;            // 10*1024*320
    float* part = act  + 3276800;           // 5*1024*384
    float* bgf  = part + 1966080;           // 256*256
    float* bgb  = bgf  + 65536;             // 256*256
    float* beat_hidden = bgb + 65536;       // 256*128
    float* mgf  = beat_hidden + 32768;      // 64*128
    float* mgb  = mgf  + 8192;              // 64*128
    float* meas_hidden = mgb + 8192;        // 64*64
    int*   cnt  = (int*)(meas_hidden + 4096);  // 10*1024
    int*   idx  = cnt + 10240;                  // 10*1024*64

    hipMemsetAsync(cnt, 0, EE*NN*sizeof(int), stream);
    k_csr_build<<<EE*NN, 256, 0, stream>>>(adj, cnt, idx);
    k_note_fc<<<NN, 128, 0, stream>>>(nodes, fc_w, fc_b, nh);

    for (int si = 0; si < 2; ++si){
        for (int it = 0; it < 2; ++it){
            k_gather_act<<<EE*NN, SS, 0, stream>>>(nh, cnt, idx, act);
            k_gate_gemm<<<dim3(16,3,5), 256, 0, stream>>>(act, g_wz[0], g_wr[0], g_wh[0], part);
            k_gru<<<NN/4, 128, 0, stream>>>(nh, part, g_uz[0], g_ur[0], g_uh[0],
                                            g_bz[0], g_br[0], g_bh[0]);
        }
        k_gb<<<NN/8, SS, 0, stream>>>(nh, gb_w, gb_b, nh2);
        for (int it = 0; it < 2; ++it){
            k_gather_act<<<EE*NN, SS, 0, stream>>>(nh2, cnt, idx, act);
            k_gate_gemm<<<dim3(16,3,5), 256, 0, stream>>>(act, g_wz[1], g_wr[1], g_wh[1], part);
            k_gru<<<NN/4, 128, 0, stream>>>(nh2, part, g_uz[1], g_ur[1], g_uh[1],
                                            g_bz[1], g_br[1], g_bh[1]);
        }
        k_batt_fused<<<NB, 256, 0, stream>>>(nh, nh2, batt_w, batt_b, batt_c,
                                             bwi_f, bb_f, bwi_b, bb_b, bgf, bgb);
        k_lstm_rec64<<<2, 256, 0, stream>>>(bgf, bwh_f, bgb, bwh_b, beat_hidden);
        k_matt_fused<<<NM, 128, 0, stream>>>(beat_hidden, matt_w, matt_b, matt_c,
                                             mwi_f, mb_f, mwi_b, mb_b, mgf, mgb);
        k_lstm_rec32<<<2, 64, 0, stream>>>(mgf, mwh_f, mgb, mwh_b, meas_hidden);
        if (si == 0)
            k_spans<<<NN, SS, 0, stream>>>(nh, beat_hidden, meas_hidden, bn, mn);
        else
            k_spans_out<<<NN, 448, 0, stream>>>(beat_hidden, meas_hidden, nh, nh2,
                                                bn, mn, out);
    }
}

// Round 5
// 1576.164 us; speedup vs baseline: 1.0386x; 1.0123x over previous
//
#include <hip/hip_runtime.h>
#include <math.h>

// ---------------------------------------------------------------------------
// IsgnBeatMeasEncoder — round 9: packed-FP32 FMA everywhere issue-bound.
// Round-8 post-mortem: VALUBusy 0.26% chip-wide on rec64 = ~33% on its 2
// active CUs -> step = 810 cy at the ~270 VALU cy/step the code issues
// => CLOCK ~= 1.37 GHz (not 2.4). All issue-bound kernels cost 1.75x the
// 2.4GHz model: k_gate_gemm models to ~30us x8 = 240us (under top-5 cutoff).
// Round 9: v_pk_fma_f32 (2 f32 per 2-cy issue; proven in rec32 since r5):
//   - gate_gemm: 8x4 outer product -> 16 pkfma/k with op_sel B-broadcast
//     (32 -> 16 VALU ops/k). A/B as ds_read_b64 pairs.
//   - rec64: 64-FMA h-dot -> 32 elementwise pkfma (~270 -> ~165 cy/step).
//   - gb/batt/matt: LDS-transposed activations (j-pairs adjacent) ->
//     j-packed pkfma; pre-GEMVs: contiguous v2f weight rows, elementwise.
// gru/gather/csr/spans untouched.
// ---------------------------------------------------------------------------

#define NN    1024
#define EE    10
#define INDIM 78
#define SS    320
#define SECD  128
#define NB    256
#define NM    64
#define CAP   64     // max nonzeros per adjacency column (mean ~10.2)

typedef float v2f __attribute__((ext_vector_type(2)));

__device__ __forceinline__ void pkfma(v2f& a, v2f x, v2f y){
    asm("v_pk_fma_f32 %0, %1, %2, %0" : "+v"(a) : "v"(x), "v"(y));
}
// a.lo += x.lo*b.lo ; a.hi += x.hi*b.lo   (broadcast LOW half of b)
__device__ __forceinline__ void pkfma_blo(v2f& a, v2f x, v2f b){
    asm("v_pk_fma_f32 %0, %1, %2, %0 op_sel:[0,0,0] op_sel_hi:[1,0,1]"
        : "+v"(a) : "v"(x), "v"(b));
}
// a.lo += x.lo*b.hi ; a.hi += x.hi*b.hi   (broadcast HIGH half of b)
__device__ __forceinline__ void pkfma_bhi(v2f& a, v2f x, v2f b){
    asm("v_pk_fma_f32 %0, %1, %2, %0 op_sel:[0,1,0] op_sel_hi:[1,1,1]"
        : "+v"(a) : "v"(x), "v"(b));
}

__device__ __forceinline__ float fsig(float x){
    return __builtin_amdgcn_rcpf(1.f + __expf(-x));
}
__device__ __forceinline__ float ftanh(float x){
    // tanh(x) = 1 - 2/(exp(2x)+1); exp overflow -> inf -> rcp -> 0 -> 1 (correct)
    return 1.f - 2.f*__builtin_amdgcn_rcpf(1.f + __expf(2.f*x));
}

// ---------------- note_fc: x0 = tanh(nodes @ W + b); nh = [0(192) | x0] ------------
__global__ void k_note_fc(const float* __restrict__ nodes, const float* __restrict__ W,
                          const float* __restrict__ b, float* __restrict__ nh){
    int n = blockIdx.x, s = threadIdx.x;           // 128 threads
    __shared__ float xrow[INDIM];
    if (s < INDIM) xrow[s] = nodes[n*INDIM + s];
    __syncthreads();
    float acc = b[s];
    for (int k = 0; k < INDIM; ++k) acc += xrow[k]*W[k*128 + s];
    nh[n*SS + 192 + s] = ftanh(acc);
    nh[n*SS + s] = 0.f;
    if (s < 64) nh[n*SS + 128 + s] = 0.f;
}

// ---------------- CSR build: for each (e, column n) list of source rows m ----------
__global__ void k_csr_build(const float* __restrict__ adj, int* __restrict__ cnt,
                            int* __restrict__ idx){
    int em = blockIdx.x;                   // e*NN + m  (row of adj[e])
    int e = em / NN, m = em % NN;
    const float* row = adj + (size_t)em * NN;
    for (int n = threadIdx.x; n < NN; n += blockDim.x){
        if (row[n] != 0.f){
            int p = atomicAdd(&cnt[e*NN + n], 1);
            if (p < CAP) idx[((size_t)e*NN + n)*CAP + p] = m;
        }
    }
}

// ---------------- act[e,n,f] = sum over column list of x[m,f] ----------------------
__global__ void k_gather_act(const float* __restrict__ x, const int* __restrict__ cnt,
                             const int* __restrict__ idx, float* __restrict__ act){
    int en = blockIdx.x, f = threadIdx.x;  // 320 threads
    int c = cnt[en]; if (c > CAP) c = CAP;
    const int* lst = idx + (size_t)en*CAP;
    float acc = 0.f;
    for (int j = 0; j < c; ++j) acc += x[lst[j]*SS + f];
    act[(size_t)en*SS + f] = acc;
}

// ---------------- gate GEMM: part[z][n][g*128+s] = sum_{e in pair z, f} act*w -------
// Inner loop: 16 v_pk_fma_f32 per k (rows packed in pairs, B broadcast via
// op_sel) instead of 32 scalar FMA.
__global__ __launch_bounds__(256) void k_gate_gemm(const float* __restrict__ act,
        const float* __restrict__ wz, const float* __restrict__ wr,
        const float* __restrict__ wh, float* __restrict__ part){
    __shared__ float A[32*76];     // [kk][row], pad 76
    __shared__ float B[32*132];    // [kk][col], pad 132
    int nt = blockIdx.x, g = blockIdx.y, z = blockIdx.z;
    const float* W = (g==0) ? wz : ((g==1) ? wr : wh);
    int tid = threadIdx.x;
    int tx = tid & 31;             // cols tx*4 .. +3
    int ty = tid >> 5;             // rows ty*8 .. +7
    v2f acc[4][4];                 // [row-pair i2][col j]; .x=row 2i2, .y=row 2i2+1
    #pragma unroll
    for (int i=0;i<4;i++)
        #pragma unroll
        for (int j=0;j<4;j++) acc[i][j] = (v2f){0.f,0.f};
    for (int eh = 0; eh < 2; ++eh){
        int e = z*2 + eh;
        const float* Ae = act + (size_t)e*NN*SS + (size_t)nt*64*SS;
        const float* We = W   + (size_t)e*SS*SECD;
        for (int kc = 0; kc < SS; kc += 32){
            #pragma unroll
            for (int i=0;i<2;i++){                 // A: 64 rows x 32 k
                int lin4 = tid + i*256;            // 512 float4
                int r  = lin4 >> 3;
                int k4 = (lin4 & 7) << 2;
                float4 v = *(const float4*)(Ae + r*SS + kc + k4);
                A[(k4+0)*76 + r] = v.x; A[(k4+1)*76 + r] = v.y;
                A[(k4+2)*76 + r] = v.z; A[(k4+3)*76 + r] = v.w;
            }
            #pragma unroll
            for (int i=0;i<4;i++){                 // B: 32 k x 128 cols
                int lin4 = tid + i*256;            // 1024 float4
                int kk = lin4 >> 5;
                int c4 = (lin4 & 31) << 2;
                *((float4*)(B + kk*132 + c4)) = *(const float4*)(We + (kc+kk)*SECD + c4);
            }
            __syncthreads();
            #pragma unroll 8
            for (int k=0;k<32;k++){
                const v2f* A2 = (const v2f*)(A + k*76 + ty*8);   // 8B-aligned
                const v2f* B2 = (const v2f*)(B + k*132 + tx*4);  // 8B-aligned
                v2f a0=A2[0], a1=A2[1], a2=A2[2], a3=A2[3];
                v2f b01=B2[0], b23=B2[1];
                pkfma_blo(acc[0][0], a0, b01); pkfma_bhi(acc[0][1], a0, b01);
                pkfma_blo(acc[0][2], a0, b23); pkfma_bhi(acc[0][3], a0, b23);
                pkfma_blo(acc[1][0], a1, b01); pkfma_bhi(acc[1][1], a1, b01);
                pkfma_blo(acc[1][2], a1, b23); pkfma_bhi(acc[1][3], a1, b23);
                pkfma_blo(acc[2][0], a2, b01); pkfma_bhi(acc[2][1], a2, b01);
                pkfma_blo(acc[2][2], a2, b23); pkfma_bhi(acc[2][3], a2, b23);
                pkfma_blo(acc[3][0], a3, b01); pkfma_bhi(acc[3][1], a3, b01);
                pkfma_blo(acc[3][2], a3, b23); pkfma_bhi(acc[3][3], a3, b23);
            }
            __syncthreads();
        }
    }
    float* P = part + ((size_t)z*NN + (size_t)nt*64)*384 + g*SECD;
    #pragma unroll
    for (int i2=0;i2<4;i2++){
        int r0 = ty*8 + i2*2;
        *(float4*)(P + (size_t)r0*384 + tx*4) =
            make_float4(acc[i2][0].x, acc[i2][1].x, acc[i2][2].x, acc[i2][3].x);
        *(float4*)(P + (size_t)(r0+1)*384 + tx*4) =
            make_float4(acc[i2][0].y, acc[i2][1].y, acc[i2][2].y, acc[i2][3].y);
    }
}

// ---------------- GRU update (in place on x's last 128 cols), 4 notes/block --------
__global__ void k_gru(float* __restrict__ x, const float* __restrict__ part,
        const float* __restrict__ uz, const float* __restrict__ ur, const float* __restrict__ uh,
        const float* __restrict__ bz, const float* __restrict__ br, const float* __restrict__ bh){
    int n0 = blockIdx.x*4, s = threadIdx.x;        // 128 threads
    __shared__ float xs[4][SECD], rx[4][SECD];
    #pragma unroll
    for (int j=0;j<4;j++) xs[j][s] = x[(n0+j)*SS + 192 + s];
    __syncthreads();
    float mz[4]={0,0,0,0}, mr[4]={0,0,0,0}, mh[4]={0,0,0,0};
    for (int sp=0; sp<5; sp++){
        const float* Pp = part + ((size_t)sp*NN + n0)*384;
        #pragma unroll
        for (int j=0;j<4;j++){
            mz[j] += Pp[j*384 + s];
            mr[j] += Pp[j*384 + 128 + s];
            mh[j] += Pp[j*384 + 256 + s];
        }
    }
    float dz[4]={0,0,0,0}, dr[4]={0,0,0,0};
    for (int k=0;k<SECD;k++){
        float wz_ = uz[k*SECD + s], wr_ = ur[k*SECD + s];
        #pragma unroll
        for (int j=0;j<4;j++){ float xv = xs[j][k]; dz[j] += xv*wz_; dr[j] += xv*wr_; }
    }
    float zz[4], rr[4];
    #pragma unroll
    for (int j=0;j<4;j++){
        zz[j] = fsig(mz[j] + dz[j] + bz[s]);
        rr[j] = fsig(mr[j] + dr[j] + br[s]);
        rx[j][s] = rr[j]*xs[j][s];
    }
    __syncthreads();
    float dh[4]={0,0,0,0};
    for (int k=0;k<SECD;k++){
        float wh_ = uh[k*SECD + s];
        #pragma unroll
        for (int j=0;j<4;j++) dh[j] += rx[j][k]*wh_;
    }
    #pragma unroll
    for (int j=0;j<4;j++){
        float h = ftanh(mh[j] + dh[j] + bh[s]);
        x[(n0+j)*SS + 192 + s] = (1.f - zz[j])*xs[j][s] + rr[j]*h;
    }
}

// ---------------- nb = relu(nh @ gb_w + gb_b) -> nh2, transposed tile + pkfma ------
__global__ void k_gb(const float* __restrict__ nh, const float* __restrict__ W,
                     const float* __restrict__ b, float* __restrict__ nb){
    int n0 = blockIdx.x*8, s = threadIdx.x;        // 320 threads
    __shared__ float xr_t[SS*8];                   // [k][j] — j-pairs adjacent
    {
        float v0 = nh[(n0+0)*SS + s], v1 = nh[(n0+1)*SS + s];
        float v2 = nh[(n0+2)*SS + s], v3 = nh[(n0+3)*SS + s];
        float v4 = nh[(n0+4)*SS + s], v5 = nh[(n0+5)*SS + s];
        float v6 = nh[(n0+6)*SS + s], v7 = nh[(n0+7)*SS + s];
        *(float4*)(xr_t + s*8 + 0) = make_float4(v0,v1,v2,v3);
        *(float4*)(xr_t + s*8 + 4) = make_float4(v4,v5,v6,v7);
    }
    __syncthreads();
    float bv = b[s];
    v2f a01={bv,bv}, a23={bv,bv}, a45={bv,bv}, a67={bv,bv};
    for (int k=0;k<SS;k++){
        float wv = W[k*SS + s];
        v2f ws = {wv, wv};
        const v2f* xp = (const v2f*)(xr_t + k*8);  // uniform addr -> broadcast
        pkfma(a01, xp[0], ws);
        pkfma(a23, xp[1], ws);
        pkfma(a45, xp[2], ws);
        pkfma(a67, xp[3], ws);
    }
    nb[(n0+0)*SS + s] = fmaxf(a01.x, 0.f);
    nb[(n0+1)*SS + s] = fmaxf(a01.y, 0.f);
    nb[(n0+2)*SS + s] = fmaxf(a23.x, 0.f);
    nb[(n0+3)*SS + s] = fmaxf(a23.y, 0.f);
    nb[(n0+4)*SS + s] = fmaxf(a45.x, 0.f);
    nb[(n0+5)*SS + s] = fmaxf(a45.y, 0.f);
    nb[(n0+6)*SS + s] = fmaxf(a67.x, 0.f);
    nb[(n0+7)*SS + s] = fmaxf(a67.y, 0.f);
}

// ---------------- FUSED beat attention + lstm_pre (transposed tile + pkfma) --------
__global__ __launch_bounds__(256) void k_batt_fused(
        const float* __restrict__ nh, const float* __restrict__ nh2,
        const float* __restrict__ W, const float* __restrict__ b,
        const float* __restrict__ cvec,
        const float* __restrict__ wi_f, const float* __restrict__ b_f,
        const float* __restrict__ wi_b, const float* __restrict__ b_b,
        float* __restrict__ gf, float* __restrict__ gbo){
    int g = blockIdx.x, s = threadIdx.x;           // 256 threads
    __shared__ float xr_t[256*4];                  // [k][j]
    __shared__ float simw[4][8];
    __shared__ float wgt[4][8];
    __shared__ float bnode[256];
    {
        float c0,c1,c2,c3;
        if (s < 128){
            c0 = nh[(g*4+0)*SS + 192 + s]; c1 = nh[(g*4+1)*SS + 192 + s];
            c2 = nh[(g*4+2)*SS + 192 + s]; c3 = nh[(g*4+3)*SS + 192 + s];
        } else {
            c0 = nh2[(g*4+0)*SS + 64 + s]; c1 = nh2[(g*4+1)*SS + 64 + s];
            c2 = nh2[(g*4+2)*SS + 64 + s]; c3 = nh2[(g*4+3)*SS + 64 + s];
        }
        *(float4*)(xr_t + s*4) = make_float4(c0,c1,c2,c3);
    }
    __syncthreads();
    float bias = b[s];
    v2f ac01 = {bias,bias}, ac23 = {bias,bias};
    for (int k=0;k<256;k++){
        float wv = W[k*256 + s];
        v2f ws = {wv, wv};
        const v2f* xp = (const v2f*)(xr_t + k*4);
        pkfma(ac01, xp[0], ws);
        pkfma(ac23, xp[1], ws);
    }
    float accj[4] = {ac01.x, ac01.y, ac23.x, ac23.y};
    float cv = cvec[s];
    int h = s >> 5;                                // head (HD=32)
    #pragma unroll
    for (int j=0;j<4;j++){
        float p = ftanh(accj[j])*cv;
        #pragma unroll
        for (int off=16; off>0; off>>=1) p += __shfl_down(p, off);
        if ((s & 31) == 0) simw[j][h] = p;
    }
    __syncthreads();
    if (s < 8){
        float v0=simw[0][s], v1=simw[1][s], v2=simw[2][s], v3=simw[3][s];
        float mx = fmaxf(fmaxf(v0,v1), fmaxf(v2,v3));
        float e0=__expf(v0-mx), e1=__expf(v1-mx), e2=__expf(v2-mx), e3=__expf(v3-mx);
        float den = e0+e1+e2+e3;
        wgt[0][s]=e0/den; wgt[1][s]=e1/den; wgt[2][s]=e2/den; wgt[3][s]=e3/den;
    }
    __syncthreads();
    float4 xs4 = *(const float4*)(xr_t + s*4);
    float o = xs4.x*wgt[0][h] + xs4.y*wgt[1][h] + xs4.z*wgt[2][h] + xs4.w*wgt[3][h];
    bnode[s] = o;
    __syncthreads();
    // pre-GEMV, both directions: contiguous weight rows as v2f, elementwise pkfma
    v2f afA = {b_f[s], 0.f}, afB = {0.f, 0.f};
    v2f abA = {b_b[s], 0.f}, abB = {0.f, 0.f};
    const v2f* wfp = (const v2f*)(wi_f + (size_t)s*256);
    const v2f* wbp = (const v2f*)(wi_b + (size_t)s*256);
    const v2f* bp  = (const v2f*)bnode;
    for (int k2=0;k2<128;k2+=2){
        v2f x01 = bp[k2], x23 = bp[k2+1];
        pkfma(afA, wfp[k2], x01); pkfma(afB, wfp[k2+1], x23);
        pkfma(abA, wbp[k2], x01); pkfma(abB, wbp[k2+1], x23);
    }
    gf [g*256 + s] = (afA.x + afA.y) + (afB.x + afB.y);
    gbo[g*256 + s] = (abA.x + abA.y) + (abB.x + abB.y);
}

// ---------------- FUSED measure attention + lstm_pre -------------------------------
__global__ __launch_bounds__(128) void k_matt_fused(
        const float* __restrict__ bh,   // beat_hidden [256][128]
        const float* __restrict__ W, const float* __restrict__ b,
        const float* __restrict__ cvec,
        const float* __restrict__ wi_f, const float* __restrict__ b_f,
        const float* __restrict__ wi_b, const float* __restrict__ b_b,
        float* __restrict__ gf, float* __restrict__ gbo){
    int g = blockIdx.x, s = threadIdx.x;           // 128 threads
    __shared__ float xr_t[128*4];                  // [k][j]
    __shared__ float simw[4][8];
    __shared__ float wgt[4][8];
    __shared__ float mnode[128];
    {
        float c0 = bh[(g*4+0)*128 + s], c1 = bh[(g*4+1)*128 + s];
        float c2 = bh[(g*4+2)*128 + s], c3 = bh[(g*4+3)*128 + s];
        *(float4*)(xr_t + s*4) = make_float4(c0,c1,c2,c3);
    }
    __syncthreads();
    float bias = b[s];
    v2f ac01 = {bias,bias}, ac23 = {bias,bias};
    for (int k=0;k<128;k++){
        float wv = W[k*128 + s];
        v2f ws = {wv, wv};
        const v2f* xp = (const v2f*)(xr_t + k*4);
        pkfma(ac01, xp[0], ws);
        pkfma(ac23, xp[1], ws);
    }
    float accj[4] = {ac01.x, ac01.y, ac23.x, ac23.y};
    float cv = cvec[s];
    int h = s >> 4;                                // head (HD=16)
    #pragma unroll
    for (int j=0;j<4;j++){
        float p = ftanh(accj[j])*cv;
        #pragma unroll
        for (int off=8; off>0; off>>=1) p += __shfl_down(p, off);
        if ((s & 15) == 0) simw[j][h] = p;
    }
    __syncthreads();
    if (s < 8){
        float v0=simw[0][s], v1=simw[1][s], v2=simw[2][s], v3=simw[3][s];
        float mx = fmaxf(fmaxf(v0,v1), fmaxf(v2,v3));
        float e0=__expf(v0-mx), e1=__expf(v1-mx), e2=__expf(v2-mx), e3=__expf(v3-mx);
        float den = e0+e1+e2+e3;
        wgt[0][s]=e0/den; wgt[1][s]=e1/den; wgt[2][s]=e2/den; wgt[3][s]=e3/den;
    }
    __syncthreads();
    float4 xs4 = *(const float4*)(xr_t + s*4);
    float o = xs4.x*wgt[0][h] + xs4.y*wgt[1][h] + xs4.z*wgt[2][h] + xs4.w*wgt[3][h];
    mnode[s] = o;
    __syncthreads();
    v2f afA = {b_f[s], 0.f}, afB = {0.f, 0.f};
    v2f abA = {b_b[s], 0.f}, abB = {0.f, 0.f};
    const v2f* wfp = (const v2f*)(wi_f + (size_t)s*128);
    const v2f* wbp = (const v2f*)(wi_b + (size_t)s*128);
    const v2f* bp  = (const v2f*)mnode;
    for (int k2=0;k2<64;k2+=2){
        v2f x01 = bp[k2], x23 = bp[k2+1];
        pkfma(afA, wfp[k2], x01); pkfma(afB, wfp[k2+1], x23);
        pkfma(abA, wbp[k2], x01); pkfma(abB, wbp[k2+1], x23);
    }
    gf [g*128 + s] = (afA.x + afA.y) + (afB.x + afB.y);
    gbo[g*128 + s] = (abA.x + abA.y) + (abB.x + abB.y);
}

// ---------------- LSTM recurrence, H=64 T=256: round-6 structure + pkfma dot -------
// 4 waves, redundant gate phase, gsum parity double-buffer, 1 barrier/step.
// h-dot: 32 elementwise v_pk_fma_f32 (64 weight VGPRs as 32 named v2f — the
// register demand proven to registerize under waves_per_eu(1,1)).
__global__ __launch_bounds__(256)
__attribute__((amdgpu_waves_per_eu(1, 1)))
void k_lstm_rec64(
        const float* __restrict__ gin_f, const float* __restrict__ wh_f,
        const float* __restrict__ gin_b, const float* __restrict__ wh_b,
        float* __restrict__ hid /* [T][128] */){
    const int H = 64, T = 256;
    int dir = blockIdx.x;
    const float* gin = dir ? gin_b : gin_f;
    const float* wh  = dir ? wh_b  : wh_f;
    int gi = threadIdx.x;                  // gate-row in [0, 256)
    int l  = gi & 63;                      // h-index this gate feeds
    const v2f* wp = (const v2f*)(wh + (size_t)gi*H);
    v2f w00=wp[0], w01=wp[1], w02=wp[2], w03=wp[3], w04=wp[4], w05=wp[5], w06=wp[6], w07=wp[7],
        w08=wp[8], w09=wp[9], w10=wp[10],w11=wp[11],w12=wp[12],w13=wp[13],w14=wp[14],w15=wp[15],
        w16=wp[16],w17=wp[17],w18=wp[18],w19=wp[19],w20=wp[20],w21=wp[21],w22=wp[22],w23=wp[23],
        w24=wp[24],w25=wp[25],w26=wp[26],w27=wp[27],w28=wp[28],w29=wp[29],w30=wp[30],w31=wp[31];
    __shared__ __align__(16) float hs[H];
    __shared__ float gsum[2][4*H];
    float c = 0.f;
    if (gi < H) hs[gi] = 0.f;
    __syncthreads();
    float gcur = gin[(dir ? (T-1) : 0)*4*H + gi];
    for (int step=0; step<T; step++){
        int t = dir ? (T-1-step) : step;
        float gnext = 0.f;
        if (step+1 < T) gnext = gin[(dir ? (T-2-step) : (step+1))*4*H + gi];
        const v2f* hv = (const v2f*)hs;            // uniform addr -> LDS broadcast
        v2f h00=hv[0], h01=hv[1], h02=hv[2], h03=hv[3], h04=hv[4], h05=hv[5], h06=hv[6], h07=hv[7],
            h08=hv[8], h09=hv[9], h10=hv[10],h11=hv[11],h12=hv[12],h13=hv[13],h14=hv[14],h15=hv[15],
            h16=hv[16],h17=hv[17],h18=hv[18],h19=hv[19],h20=hv[20],h21=hv[21],h22=hv[22],h23=hv[23],
            h24=hv[24],h25=hv[25],h26=hv[26],h27=hv[27],h28=hv[28],h29=hv[29],h30=hv[30],h31=hv[31];
        v2f A0={gcur,0.f}, A1={0.f,0.f}, A2={0.f,0.f}, A3={0.f,0.f};
        pkfma(A0,w00,h00); pkfma(A1,w01,h01); pkfma(A2,w02,h02); pkfma(A3,w03,h03);
        pkfma(A0,w04,h04); pkfma(A1,w05,h05); pkfma(A2,w06,h06); pkfma(A3,w07,h07);
        pkfma(A0,w08,h08); pkfma(A1,w09,h09); pkfma(A2,w10,h10); pkfma(A3,w11,h11);
        pkfma(A0,w12,h12); pkfma(A1,w13,h13); pkfma(A2,w14,h14); pkfma(A3,w15,h15);
        pkfma(A0,w16,h16); pkfma(A1,w17,h17); pkfma(A2,w18,h18); pkfma(A3,w19,h19);
        pkfma(A0,w20,h20); pkfma(A1,w21,h21); pkfma(A2,w22,h22); pkfma(A3,w23,h23);
        pkfma(A0,w24,h24); pkfma(A1,w25,h25); pkfma(A2,w26,h26); pkfma(A3,w27,h27);
        pkfma(A0,w28,h28); pkfma(A1,w29,h29); pkfma(A2,w30,h30); pkfma(A3,w31,h31);
        float* gs = gsum[step & 1];
        gs[gi] = ((A0.x+A0.y) + (A1.x+A1.y)) + ((A2.x+A2.y) + (A3.x+A3.y));
        __syncthreads();                           // the ONLY barrier per step
        float ig = gs[l], fg = gs[H+l], gg = gs[2*H+l], og = gs[3*H+l];
        c = fsig(fg)*c + fsig(ig)*ftanh(gg);       // all waves: identical update
        float hn = fsig(og)*ftanh(c);
        hs[l] = hn;                                // every wave writes full hs
        if (gi < H) hid[t*2*H + dir*H + gi] = hn;  // one wave publishes
        gcur = gnext;
    }
}

// ---------------- LSTM recurrence, H=32 T=64: single wave, NO barrier --------------
// (round-7 form, verified) Lane gi owns rows {gi, 64+gi}; partner gates via
// __shfl(x, gi^32). Single wave => LDS in-order, no barrier. Prefetch-2.
__global__ __launch_bounds__(64)
__attribute__((amdgpu_waves_per_eu(1, 1)))
void k_lstm_rec32(
        const float* __restrict__ gin_f, const float* __restrict__ wh_f,
        const float* __restrict__ gin_b, const float* __restrict__ wh_b,
        float* __restrict__ hid /* [T][64] */){
    const int H = 32, T = 64;
    int dir = blockIdx.x;
    const float* gin = dir ? gin_b : gin_f;
    const float* wh  = dir ? wh_b  : wh_f;
    int gi = threadIdx.x;                  // 0..63
    v2f wA[16], wB[16];
    {
        const v2f* rA = (const v2f*)(wh + (size_t)(     gi)*H);   // rows 0..63:  i|f
        const v2f* rB = (const v2f*)(wh + (size_t)(64 + gi)*H);   // rows 64..127: g|o
        #pragma unroll
        for (int k=0;k<16;k++){ wA[k]=rA[k]; wB[k]=rB[k]; }
    }
    __shared__ __align__(16) float hs[H];
    float c = 0.f;
    if (gi < H) hs[gi] = 0.f;
    __syncthreads();
    const float* gp = gin + gi;
    int ts0 = dir ? (T-1) : 0, ts1 = dir ? (T-2) : 1;
    float g0 = gp[ts0*128], g1 = gp[ts0*128 + 64];
    float n0 = gp[ts1*128], n1 = gp[ts1*128 + 64];
    bool lo = (gi < H);
    for (int step=0; step<T; step++){
        int t = dir ? (T-1-step) : step;
        float p0=0.f, p1=0.f;
        if (step+2 < T){
            int tp = dir ? (T-3-step) : (step+2);
            p0 = gp[tp*128]; p1 = gp[tp*128 + 64];
        }
        v2f aA = {g0, 0.f}, aB = {g1, 0.f};
        const v2f* hv = (const v2f*)hs;
        #pragma unroll
        for (int k=0;k<16;k++){
            v2f h2 = hv[k];
            pkfma(aA, wA[k], h2);
            pkfma(aB, wB[k], h2);
        }
        float sA = aA.x + aA.y;            // lane<32: i ; lane>=32: f
        float sB = aB.x + aB.y;            // lane<32: g ; lane>=32: o
        float pA = __shfl(sA, gi ^ 32);
        float pB = __shfl(sB, gi ^ 32);
        float i_ = lo ? sA : pA;
        float f_ = lo ? pA : sA;
        float g_ = lo ? sB : pB;
        float o_ = lo ? pB : sB;
        c = fsig(f_)*c + fsig(i_)*ftanh(g_);
        float hn = fsig(o_)*ftanh(c);
        if (lo){
            hid[t*2*H + dir*H + gi] = hn;
            hs[gi] = hn;                   // same wave: in-order LDS, no barrier
        }
        g0 = n0; g1 = n1; n0 = p0; n1 = p1;
    }
}

// ---------------- si=0: rebuild nh in place = [beat_span | meas_span | nh_sec] -----
__global__ void k_spans(float* __restrict__ nh, const float* __restrict__ bh,
                        const float* __restrict__ mh,
                        const int* __restrict__ bn, const int* __restrict__ mn){
    int n = blockIdx.x, s = threadIdx.x;           // 320 threads
    float v;
    if (s < 128)      v = bh[bn[n]*128 + s];
    else if (s < 192) v = mh[mn[n]*64 + (s-128)];
    else              v = nh[n*SS + s];            // own-thread read-then-write: safe
    nh[n*SS + s] = v;
}

// ---------------- si=1: spans + final output fused ---------------------------------
__global__ void k_spans_out(const float* __restrict__ bh, const float* __restrict__ mh,
                            const float* __restrict__ nh, const float* __restrict__ nh2,
                            const int* __restrict__ bn, const int* __restrict__ mn,
                            float* __restrict__ out){
    int n = blockIdx.x, s = threadIdx.x;           // 448 threads
    float v;
    if (s < 128)      v = bh[bn[n]*128 + s];
    else if (s < 192) v = mh[mn[n]*64 + (s-128)];
    else if (s < 320) v = nh[n*SS + s];
    else              v = nh2[n*SS + 192 + (s-320)];
    out[n*448 + s] = v;
}

// ===========================================================================
extern "C" void kernel_launch(void* const* d_in, const int* in_sizes, int n_in,
                              void* d_out, int out_size, void* d_ws, size_t ws_size,
                              hipStream_t stream) {
    const float* nodes    = (const float*)d_in[0];
    const float* adj      = (const float*)d_in[1];
    const int*   bn       = (const int*)  d_in[2];
    const int*   mn       = (const int*)  d_in[3];
    const float* fc_w     = (const float*)d_in[6];
    const float* fc_b     = (const float*)d_in[7];
    const float* g_wz[2]  = {(const float*)d_in[8],  (const float*)d_in[17]};
    const float* g_wr[2]  = {(const float*)d_in[9],  (const float*)d_in[18]};
    const float* g_wh[2]  = {(const float*)d_in[10], (const float*)d_in[19]};
    const float* g_uz[2]  = {(const float*)d_in[11], (const float*)d_in[20]};
    const float* g_ur[2]  = {(const float*)d_in[12], (const float*)d_in[21]};
    const float* g_uh[2]  = {(const float*)d_in[13], (const float*)d_in[22]};
    const float* g_bz[2]  = {(const float*)d_in[14], (const float*)d_in[23]};
    const float* g_br[2]  = {(const float*)d_in[15], (const float*)d_in[24]};
    const float* g_bh[2]  = {(const float*)d_in[16], (const float*)d_in[25]};
    const float* gb_w     = (const float*)d_in[26];
    const float* gb_b     = (const float*)d_in[27];
    const float* batt_w   = (const float*)d_in[28];
    const float* batt_b   = (const float*)d_in[29];
    const float* batt_c   = (const float*)d_in[30];
    const float* matt_w   = (const float*)d_in[31];
    const float* matt_b   = (const float*)d_in[32];
    const float* matt_c   = (const float*)d_in[33];
    const float* bwi_f    = (const float*)d_in[34];
    const float* bwh_f    = (const float*)d_in[35];
    const float* bb_f     = (const float*)d_in[36];
    const float* bwi_b    = (const float*)d_in[37];
    const float* bwh_b    = (const float*)d_in[38];
    const float* bb_b     = (const float*)d_in[39];
    const float* mwi_f    = (const float*)d_in[40];
    const float* mwh_f    = (const float*)d_in[41];
    const float* mb_f     = (const float*)d_in[42];
    const float* mwi_b    = (const float*)d_in[43];
    const float* mwh_b    = (const float*)d_in[44];
    const float* mb_b     = (const float*)d_in[45];
    float* out = (float*)d_out;

    // --- workspace layout (floats; ~27 MB) ---
    float* W_   = (float*)d_ws;
    float* nh   = W_;                       // 1024*320
    float* nh2  = nh   + 327680;            // 1024*320
    float* act  = nh2  + 327680;            // 10*1024*320
    float* part = act  + 3276800;           // 5*1024*384
    float* bgf  = part + 1966080;           // 256*256
    float* bgb  = bgf  + 65536;             // 256*256
    float* beat_hidden = bgb + 65536;       // 256*128
    float* mgf  = beat_hidden + 32768;      // 64*128
    float* mgb  = mgf  + 8192;              // 64*128
    float* meas_hidden = mgb + 8192;        // 64*64
    int*   cnt  = (int*)(meas_hidden + 4096);  // 10*1024
    int*   idx  = cnt + 10240;                  // 10*1024*64

    hipMemsetAsync(cnt, 0, EE*NN*sizeof(int), stream);
    k_csr_build<<<EE*NN, 256, 0, stream>>>(adj, cnt, idx);
    k_note_fc<<<NN, 128, 0, stream>>>(nodes, fc_w, fc_b, nh);

    for (int si = 0; si < 2; ++si){
        for (int it = 0; it < 2; ++it){
            k_gather_act<<<EE*NN, SS, 0, stream>>>(nh, cnt, idx, act);
            k_gate_gemm<<<dim3(16,3,5), 256, 0, stream>>>(act, g_wz[0], g_wr[0], g_wh[0], part);
            k_gru<<<NN/4, 128, 0, stream>>>(nh, part, g_uz[0], g_ur[0], g_uh[0],
                                            g_bz[0], g_br[0], g_bh[0]);
        }
        k_gb<<<NN/8, SS, 0, stream>>>(nh, gb_w, gb_b, nh2);
        for (int it = 0; it < 2; ++it){
            k_gather_act<<<EE*NN, SS, 0, stream>>>(nh2, cnt, idx, act);
            k_gate_gemm<<<dim3(16,3,5), 256, 0, stream>>>(act, g_wz[1], g_wr[1], g_wh[1], part);
            k_gru<<<NN/4, 128, 0, stream>>>(nh2, part, g_uz[1], g_ur[1], g_uh[1],
                                            g_bz[1], g_br[1], g_bh[1]);
        }
        k_batt_fused<<<NB, 256, 0, stream>>>(nh, nh2, batt_w, batt_b, batt_c,
                                             bwi_f, bb_f, bwi_b, bb_b, bgf, bgb);
        k_lstm_rec64<<<2, 256, 0, stream>>>(bgf, bwh_f, bgb, bwh_b, beat_hidden);
        k_matt_fused<<<NM, 128, 0, stream>>>(beat_hidden, matt_w, matt_b, matt_c,
                                             mwi_f, mb_f, mwi_b, mb_b, mgf, mgb);
        k_lstm_rec32<<<2, 64, 0, stream>>>(mgf, mwh_f, mgb, mwh_b, meas_hidden);
        if (si == 0)
            k_spans<<<NN, SS, 0, stream>>>(nh, beat_hidden, meas_hidden, bn, mn);
        else
            k_spans_out<<<NN, 448, 0, stream>>>(beat_hidden, meas_hidden, nh, nh2,
                                                bn, mn, out);
    }
}

// Round 6
// 1259.477 us; speedup vs baseline: 1.2997x; 1.2514x over previous
//
#include <hip/hip_runtime.h>
#include <math.h>

// ---------------------------------------------------------------------------
// IsgnBeatMeasEncoder — round 10: occupancy for the mid-tier.
// Round-9 post-mortem: rec64 pkfma WORKED (150.7 -> 120.3us). But total-minus
// -rec64 has been ~1300us for SIX rounds and ignored every ALU optimization.
// Launch gaps priced at ~2us/dispatch (r6->r8 delta) -> ~1200us of real work
// hides under the 120us top-5 cutoff. Under-occupancy suspects:
//   gate_gemm: 240 blocks = <1 block/CU, 4 waves; gru: 256 blocks, 2 waves.
// Round 10:
//   - gate_gemm v2: 32-row tiles, grid (32,3,5)=480 blocks (2/CU); B-operand
//     read restored to float4 (r8-proven bank pattern); 8 pkfma/k.
//   - gru: 2 notes/block, 512 blocks (2/CU).
//   - csr_build: float4 row scan.
//   - rec64/rec32/batt/matt/gb and all else: unchanged from round 9.
// Falsification: if total stays >=1560, mid-tier wasn't gemm/gru/csr ->
// round 11 = cooperative mega-kernel (clock/idle hypothesis).
// ---------------------------------------------------------------------------

#define NN    1024
#define EE    10
#define INDIM 78
#define SS    320
#define SECD  128
#define NB    256
#define NM    64
#define CAP   64     // max nonzeros per adjacency column (mean ~10.2)

typedef float v2f __attribute__((ext_vector_type(2)));

__device__ __forceinline__ void pkfma(v2f& a, v2f x, v2f y){
    asm("v_pk_fma_f32 %0, %1, %2, %0" : "+v"(a) : "v"(x), "v"(y));
}
// a.lo += x.lo*b.lo ; a.hi += x.hi*b.lo   (broadcast LOW half of b)
__device__ __forceinline__ void pkfma_blo(v2f& a, v2f x, v2f b){
    asm("v_pk_fma_f32 %0, %1, %2, %0 op_sel:[0,0,0] op_sel_hi:[1,0,1]"
        : "+v"(a) : "v"(x), "v"(b));
}
// a.lo += x.lo*b.hi ; a.hi += x.hi*b.hi   (broadcast HIGH half of b)
__device__ __forceinline__ void pkfma_bhi(v2f& a, v2f x, v2f b){
    asm("v_pk_fma_f32 %0, %1, %2, %0 op_sel:[0,1,0] op_sel_hi:[1,1,1]"
        : "+v"(a) : "v"(x), "v"(b));
}

__device__ __forceinline__ float fsig(float x){
    return __builtin_amdgcn_rcpf(1.f + __expf(-x));
}
__device__ __forceinline__ float ftanh(float x){
    // tanh(x) = 1 - 2/(exp(2x)+1); exp overflow -> inf -> rcp -> 0 -> 1 (correct)
    return 1.f - 2.f*__builtin_amdgcn_rcpf(1.f + __expf(2.f*x));
}

// ---------------- note_fc: x0 = tanh(nodes @ W + b); nh = [0(192) | x0] ------------
__global__ void k_note_fc(const float* __restrict__ nodes, const float* __restrict__ W,
                          const float* __restrict__ b, float* __restrict__ nh){
    int n = blockIdx.x, s = threadIdx.x;           // 128 threads
    __shared__ float xrow[INDIM];
    if (s < INDIM) xrow[s] = nodes[n*INDIM + s];
    __syncthreads();
    float acc = b[s];
    for (int k = 0; k < INDIM; ++k) acc += xrow[k]*W[k*128 + s];
    nh[n*SS + 192 + s] = ftanh(acc);
    nh[n*SS + s] = 0.f;
    if (s < 64) nh[n*SS + 128 + s] = 0.f;
}

// ---------------- CSR build: float4 scan of each adj row ---------------------------
__global__ void k_csr_build(const float* __restrict__ adj, int* __restrict__ cnt,
                            int* __restrict__ idx){
    int em = blockIdx.x;                   // e*NN + m  (row of adj[e])
    int e = em / NN, m = em % NN;
    const float4* row4 = (const float4*)(adj + (size_t)em * NN);
    int q = threadIdx.x;                   // 256 threads, 256 float4 = 1024 cols
    float4 v = row4[q];
    int n0 = q*4;
    if (v.x != 0.f){ int p = atomicAdd(&cnt[e*NN + n0+0], 1); if (p < CAP) idx[((size_t)e*NN + n0+0)*CAP + p] = m; }
    if (v.y != 0.f){ int p = atomicAdd(&cnt[e*NN + n0+1], 1); if (p < CAP) idx[((size_t)e*NN + n0+1)*CAP + p] = m; }
    if (v.z != 0.f){ int p = atomicAdd(&cnt[e*NN + n0+2], 1); if (p < CAP) idx[((size_t)e*NN + n0+2)*CAP + p] = m; }
    if (v.w != 0.f){ int p = atomicAdd(&cnt[e*NN + n0+3], 1); if (p < CAP) idx[((size_t)e*NN + n0+3)*CAP + p] = m; }
}

// ---------------- act[e,n,f] = sum over column list of x[m,f] ----------------------
__global__ void k_gather_act(const float* __restrict__ x, const int* __restrict__ cnt,
                             const int* __restrict__ idx, float* __restrict__ act){
    int en = blockIdx.x, f = threadIdx.x;  // 320 threads
    int c = cnt[en]; if (c > CAP) c = CAP;
    const int* lst = idx + (size_t)en*CAP;
    float acc = 0.f;
    for (int j = 0; j < c; ++j) acc += x[lst[j]*SS + f];
    act[(size_t)en*SS + f] = acc;
}

// ---------------- gate GEMM v2: 32-row tiles, 480 blocks, float4 B reads ------------
// Block (nt,g,z): rows nt*32..+31, gate g, e-pair z. Per thread: 4 rows x 4
// cols via 8 pkfma/k (A row-pairs packed, B broadcast via op_sel halves).
__global__ __launch_bounds__(256) void k_gate_gemm(const float* __restrict__ act,
        const float* __restrict__ wz, const float* __restrict__ wr,
        const float* __restrict__ wh, float* __restrict__ part){
    __shared__ float A[32*36];     // [kk][row], 32 rows pad 36
    __shared__ float B[32*132];    // [kk][col], pad 132
    int nt = blockIdx.x, g = blockIdx.y, z = blockIdx.z;
    const float* W = (g==0) ? wz : ((g==1) ? wr : wh);
    int tid = threadIdx.x;
    int tx = tid & 31;             // cols tx*4 .. +3
    int ty = tid >> 5;             // rows ty*4 .. +3
    v2f acc[2][4];                 // [row-pair][col]; .x=row ty*4+2rp, .y=+1
    #pragma unroll
    for (int i=0;i<2;i++)
        #pragma unroll
        for (int j=0;j<4;j++) acc[i][j] = (v2f){0.f,0.f};
    for (int eh = 0; eh < 2; ++eh){
        int e = z*2 + eh;
        const float* Ae = act + (size_t)e*NN*SS + (size_t)nt*32*SS;
        const float* We = W   + (size_t)e*SS*SECD;
        for (int kc = 0; kc < SS; kc += 32){
            {                                      // A: 32 rows x 32 k = 256 float4
                int r  = tid >> 3;
                int k4 = (tid & 7) << 2;
                float4 v = *(const float4*)(Ae + r*SS + kc + k4);
                A[(k4+0)*36 + r] = v.x; A[(k4+1)*36 + r] = v.y;
                A[(k4+2)*36 + r] = v.z; A[(k4+3)*36 + r] = v.w;
            }
            #pragma unroll
            for (int i=0;i<4;i++){                 // B: 32 k x 128 cols
                int lin4 = tid + i*256;            // 1024 float4
                int kk = lin4 >> 5;
                int c4 = (lin4 & 31) << 2;
                *((float4*)(B + kk*132 + c4)) = *(const float4*)(We + (kc+kk)*SECD + c4);
            }
            __syncthreads();
            #pragma unroll 8
            for (int k=0;k<32;k++){
                const v2f* A2 = (const v2f*)(A + k*36 + ty*4);   // wave-uniform
                v2f a01 = A2[0], a23 = A2[1];
                float4 b = *(const float4*)(B + k*132 + tx*4);   // r8-proven pattern
                v2f b01 = {b.x, b.y}, b23 = {b.z, b.w};
                pkfma_blo(acc[0][0], a01, b01); pkfma_bhi(acc[0][1], a01, b01);
                pkfma_blo(acc[0][2], a01, b23); pkfma_bhi(acc[0][3], a01, b23);
                pkfma_blo(acc[1][0], a23, b01); pkfma_bhi(acc[1][1], a23, b01);
                pkfma_blo(acc[1][2], a23, b23); pkfma_bhi(acc[1][3], a23, b23);
            }
            __syncthreads();
        }
    }
    float* P = part + ((size_t)z*NN + (size_t)nt*32)*384 + g*SECD;
    int r0 = ty*4;
    *(float4*)(P + (size_t)(r0+0)*384 + tx*4) =
        make_float4(acc[0][0].x, acc[0][1].x, acc[0][2].x, acc[0][3].x);
    *(float4*)(P + (size_t)(r0+1)*384 + tx*4) =
        make_float4(acc[0][0].y, acc[0][1].y, acc[0][2].y, acc[0][3].y);
    *(float4*)(P + (size_t)(r0+2)*384 + tx*4) =
        make_float4(acc[1][0].x, acc[1][1].x, acc[1][2].x, acc[1][3].x);
    *(float4*)(P + (size_t)(r0+3)*384 + tx*4) =
        make_float4(acc[1][0].y, acc[1][1].y, acc[1][2].y, acc[1][3].y);
}

// ---------------- GRU update, 2 notes/block (512 blocks, 2/CU) ---------------------
__global__ void k_gru(float* __restrict__ x, const float* __restrict__ part,
        const float* __restrict__ uz, const float* __restrict__ ur, const float* __restrict__ uh,
        const float* __restrict__ bz, const float* __restrict__ br, const float* __restrict__ bh){
    int n0 = blockIdx.x*2, s = threadIdx.x;        // 128 threads
    __shared__ float xs[2][SECD], rx[2][SECD];
    #pragma unroll
    for (int j=0;j<2;j++) xs[j][s] = x[(n0+j)*SS + 192 + s];
    __syncthreads();
    float mz[2]={0,0}, mr[2]={0,0}, mh[2]={0,0};
    for (int sp=0; sp<5; sp++){
        const float* Pp = part + ((size_t)sp*NN + n0)*384;
        #pragma unroll
        for (int j=0;j<2;j++){
            mz[j] += Pp[j*384 + s];
            mr[j] += Pp[j*384 + 128 + s];
            mh[j] += Pp[j*384 + 256 + s];
        }
    }
    float dz[2]={0,0}, dr[2]={0,0};
    for (int k=0;k<SECD;k++){
        float wz_ = uz[k*SECD + s], wr_ = ur[k*SECD + s];
        #pragma unroll
        for (int j=0;j<2;j++){ float xv = xs[j][k]; dz[j] += xv*wz_; dr[j] += xv*wr_; }
    }
    float zz[2], rr[2];
    #pragma unroll
    for (int j=0;j<2;j++){
        zz[j] = fsig(mz[j] + dz[j] + bz[s]);
        rr[j] = fsig(mr[j] + dr[j] + br[s]);
        rx[j][s] = rr[j]*xs[j][s];
    }
    __syncthreads();
    float dh[2]={0,0};
    for (int k=0;k<SECD;k++){
        float wh_ = uh[k*SECD + s];
        #pragma unroll
        for (int j=0;j<2;j++) dh[j] += rx[j][k]*wh_;
    }
    #pragma unroll
    for (int j=0;j<2;j++){
        float h = ftanh(mh[j] + dh[j] + bh[s]);
        x[(n0+j)*SS + 192 + s] = (1.f - zz[j])*xs[j][s] + rr[j]*h;
    }
}

// ---------------- nb = relu(nh @ gb_w + gb_b) -> nh2, transposed tile + pkfma ------
__global__ void k_gb(const float* __restrict__ nh, const float* __restrict__ W,
                     const float* __restrict__ b, float* __restrict__ nb){
    int n0 = blockIdx.x*8, s = threadIdx.x;        // 320 threads
    __shared__ float xr_t[SS*8];                   // [k][j] — j-pairs adjacent
    {
        float v0 = nh[(n0+0)*SS + s], v1 = nh[(n0+1)*SS + s];
        float v2 = nh[(n0+2)*SS + s], v3 = nh[(n0+3)*SS + s];
        float v4 = nh[(n0+4)*SS + s], v5 = nh[(n0+5)*SS + s];
        float v6 = nh[(n0+6)*SS + s], v7 = nh[(n0+7)*SS + s];
        *(float4*)(xr_t + s*8 + 0) = make_float4(v0,v1,v2,v3);
        *(float4*)(xr_t + s*8 + 4) = make_float4(v4,v5,v6,v7);
    }
    __syncthreads();
    float bv = b[s];
    v2f a01={bv,bv}, a23={bv,bv}, a45={bv,bv}, a67={bv,bv};
    for (int k=0;k<SS;k++){
        float wv = W[k*SS + s];
        v2f ws = {wv, wv};
        const v2f* xp = (const v2f*)(xr_t + k*8);  // uniform addr -> broadcast
        pkfma(a01, xp[0], ws);
        pkfma(a23, xp[1], ws);
        pkfma(a45, xp[2], ws);
        pkfma(a67, xp[3], ws);
    }
    nb[(n0+0)*SS + s] = fmaxf(a01.x, 0.f);
    nb[(n0+1)*SS + s] = fmaxf(a01.y, 0.f);
    nb[(n0+2)*SS + s] = fmaxf(a23.x, 0.f);
    nb[(n0+3)*SS + s] = fmaxf(a23.y, 0.f);
    nb[(n0+4)*SS + s] = fmaxf(a45.x, 0.f);
    nb[(n0+5)*SS + s] = fmaxf(a45.y, 0.f);
    nb[(n0+6)*SS + s] = fmaxf(a67.x, 0.f);
    nb[(n0+7)*SS + s] = fmaxf(a67.y, 0.f);
}

// ---------------- FUSED beat attention + lstm_pre (transposed tile + pkfma) --------
__global__ __launch_bounds__(256) void k_batt_fused(
        const float* __restrict__ nh, const float* __restrict__ nh2,
        const float* __restrict__ W, const float* __restrict__ b,
        const float* __restrict__ cvec,
        const float* __restrict__ wi_f, const float* __restrict__ b_f,
        const float* __restrict__ wi_b, const float* __restrict__ b_b,
        float* __restrict__ gf, float* __restrict__ gbo){
    int g = blockIdx.x, s = threadIdx.x;           // 256 threads
    __shared__ float xr_t[256*4];                  // [k][j]
    __shared__ float simw[4][8];
    __shared__ float wgt[4][8];
    __shared__ float bnode[256];
    {
        float c0,c1,c2,c3;
        if (s < 128){
            c0 = nh[(g*4+0)*SS + 192 + s]; c1 = nh[(g*4+1)*SS + 192 + s];
            c2 = nh[(g*4+2)*SS + 192 + s]; c3 = nh[(g*4+3)*SS + 192 + s];
        } else {
            c0 = nh2[(g*4+0)*SS + 64 + s]; c1 = nh2[(g*4+1)*SS + 64 + s];
            c2 = nh2[(g*4+2)*SS + 64 + s]; c3 = nh2[(g*4+3)*SS + 64 + s];
        }
        *(float4*)(xr_t + s*4) = make_float4(c0,c1,c2,c3);
    }
    __syncthreads();
    float bias = b[s];
    v2f ac01 = {bias,bias}, ac23 = {bias,bias};
    for (int k=0;k<256;k++){
        float wv = W[k*256 + s];
        v2f ws = {wv, wv};
        const v2f* xp = (const v2f*)(xr_t + k*4);
        pkfma(ac01, xp[0], ws);
        pkfma(ac23, xp[1], ws);
    }
    float accj[4] = {ac01.x, ac01.y, ac23.x, ac23.y};
    float cv = cvec[s];
    int h = s >> 5;                                // head (HD=32)
    #pragma unroll
    for (int j=0;j<4;j++){
        float p = ftanh(accj[j])*cv;
        #pragma unroll
        for (int off=16; off>0; off>>=1) p += __shfl_down(p, off);
        if ((s & 31) == 0) simw[j][h] = p;
    }
    __syncthreads();
    if (s < 8){
        float v0=simw[0][s], v1=simw[1][s], v2=simw[2][s], v3=simw[3][s];
        float mx = fmaxf(fmaxf(v0,v1), fmaxf(v2,v3));
        float e0=__expf(v0-mx), e1=__expf(v1-mx), e2=__expf(v2-mx), e3=__expf(v3-mx);
        float den = e0+e1+e2+e3;
        wgt[0][s]=e0/den; wgt[1][s]=e1/den; wgt[2][s]=e2/den; wgt[3][s]=e3/den;
    }
    __syncthreads();
    float4 xs4 = *(const float4*)(xr_t + s*4);
    float o = xs4.x*wgt[0][h] + xs4.y*wgt[1][h] + xs4.z*wgt[2][h] + xs4.w*wgt[3][h];
    bnode[s] = o;
    __syncthreads();
    // pre-GEMV, both directions: contiguous weight rows as v2f, elementwise pkfma
    v2f afA = {b_f[s], 0.f}, afB = {0.f, 0.f};
    v2f abA = {b_b[s], 0.f}, abB = {0.f, 0.f};
    const v2f* wfp = (const v2f*)(wi_f + (size_t)s*256);
    const v2f* wbp = (const v2f*)(wi_b + (size_t)s*256);
    const v2f* bp  = (const v2f*)bnode;
    for (int k2=0;k2<128;k2+=2){
        v2f x01 = bp[k2], x23 = bp[k2+1];
        pkfma(afA, wfp[k2], x01); pkfma(afB, wfp[k2+1], x23);
        pkfma(abA, wbp[k2], x01); pkfma(abB, wbp[k2+1], x23);
    }
    gf [g*256 + s] = (afA.x + afA.y) + (afB.x + afB.y);
    gbo[g*256 + s] = (abA.x + abA.y) + (abB.x + abB.y);
}

// ---------------- FUSED measure attention + lstm_pre -------------------------------
__global__ __launch_bounds__(128) void k_matt_fused(
        const float* __restrict__ bh,   // beat_hidden [256][128]
        const float* __restrict__ W, const float* __restrict__ b,
        const float* __restrict__ cvec,
        const float* __restrict__ wi_f, const float* __restrict__ b_f,
        const float* __restrict__ wi_b, const float* __restrict__ b_b,
        float* __restrict__ gf, float* __restrict__ gbo){
    int g = blockIdx.x, s = threadIdx.x;           // 128 threads
    __shared__ float xr_t[128*4];                  // [k][j]
    __shared__ float simw[4][8];
    __shared__ float wgt[4][8];
    __shared__ float mnode[128];
    {
        float c0 = bh[(g*4+0)*128 + s], c1 = bh[(g*4+1)*128 + s];
        float c2 = bh[(g*4+2)*128 + s], c3 = bh[(g*4+3)*128 + s];
        *(float4*)(xr_t + s*4) = make_float4(c0,c1,c2,c3);
    }
    __syncthreads();
    float bias = b[s];
    v2f ac01 = {bias,bias}, ac23 = {bias,bias};
    for (int k=0;k<128;k++){
        float wv = W[k*128 + s];
        v2f ws = {wv, wv};
        const v2f* xp = (const v2f*)(xr_t + k*4);
        pkfma(ac01, xp[0], ws);
        pkfma(ac23, xp[1], ws);
    }
    float accj[4] = {ac01.x, ac01.y, ac23.x, ac23.y};
    float cv = cvec[s];
    int h = s >> 4;                                // head (HD=16)
    #pragma unroll
    for (int j=0;j<4;j++){
        float p = ftanh(accj[j])*cv;
        #pragma unroll
        for (int off=8; off>0; off>>=1) p += __shfl_down(p, off);
        if ((s & 15) == 0) simw[j][h] = p;
    }
    __syncthreads();
    if (s < 8){
        float v0=simw[0][s], v1=simw[1][s], v2=simw[2][s], v3=simw[3][s];
        float mx = fmaxf(fmaxf(v0,v1), fmaxf(v2,v3));
        float e0=__expf(v0-mx), e1=__expf(v1-mx), e2=__expf(v2-mx), e3=__expf(v3-mx);
        float den = e0+e1+e2+e3;
        wgt[0][s]=e0/den; wgt[1][s]=e1/den; wgt[2][s]=e2/den; wgt[3][s]=e3/den;
    }
    __syncthreads();
    float4 xs4 = *(const float4*)(xr_t + s*4);
    float o = xs4.x*wgt[0][h] + xs4.y*wgt[1][h] + xs4.z*wgt[2][h] + xs4.w*wgt[3][h];
    mnode[s] = o;
    __syncthreads();
    v2f afA = {b_f[s], 0.f}, afB = {0.f, 0.f};
    v2f abA = {b_b[s], 0.f}, abB = {0.f, 0.f};
    const v2f* wfp = (const v2f*)(wi_f + (size_t)s*128);
    const v2f* wbp = (const v2f*)(wi_b + (size_t)s*128);
    const v2f* bp  = (const v2f*)mnode;
    for (int k2=0;k2<64;k2+=2){
        v2f x01 = bp[k2], x23 = bp[k2+1];
        pkfma(afA, wfp[k2], x01); pkfma(afB, wfp[k2+1], x23);
        pkfma(abA, wbp[k2], x01); pkfma(abB, wbp[k2+1], x23);
    }
    gf [g*128 + s] = (afA.x + afA.y) + (afB.x + afB.y);
    gbo[g*128 + s] = (abA.x + abA.y) + (abB.x + abB.y);
}

// ---------------- LSTM recurrence, H=64 T=256: round-9 form (best measured) --------
__global__ __launch_bounds__(256)
__attribute__((amdgpu_waves_per_eu(1, 1)))
void k_lstm_rec64(
        const float* __restrict__ gin_f, const float* __restrict__ wh_f,
        const float* __restrict__ gin_b, const float* __restrict__ wh_b,
        float* __restrict__ hid /* [T][128] */){
    const int H = 64, T = 256;
    int dir = blockIdx.x;
    const float* gin = dir ? gin_b : gin_f;
    const float* wh  = dir ? wh_b  : wh_f;
    int gi = threadIdx.x;                  // gate-row in [0, 256)
    int l  = gi & 63;                      // h-index this gate feeds
    const v2f* wp = (const v2f*)(wh + (size_t)gi*H);
    v2f w00=wp[0], w01=wp[1], w02=wp[2], w03=wp[3], w04=wp[4], w05=wp[5], w06=wp[6], w07=wp[7],
        w08=wp[8], w09=wp[9], w10=wp[10],w11=wp[11],w12=wp[12],w13=wp[13],w14=wp[14],w15=wp[15],
        w16=wp[16],w17=wp[17],w18=wp[18],w19=wp[19],w20=wp[20],w21=wp[21],w22=wp[22],w23=wp[23],
        w24=wp[24],w25=wp[25],w26=wp[26],w27=wp[27],w28=wp[28],w29=wp[29],w30=wp[30],w31=wp[31];
    __shared__ __align__(16) float hs[H];
    __shared__ float gsum[2][4*H];
    float c = 0.f;
    if (gi < H) hs[gi] = 0.f;
    __syncthreads();
    float gcur = gin[(dir ? (T-1) : 0)*4*H + gi];
    for (int step=0; step<T; step++){
        int t = dir ? (T-1-step) : step;
        float gnext = 0.f;
        if (step+1 < T) gnext = gin[(dir ? (T-2-step) : (step+1))*4*H + gi];
        const v2f* hv = (const v2f*)hs;            // uniform addr -> LDS broadcast
        v2f h00=hv[0], h01=hv[1], h02=hv[2], h03=hv[3], h04=hv[4], h05=hv[5], h06=hv[6], h07=hv[7],
            h08=hv[8], h09=hv[9], h10=hv[10],h11=hv[11],h12=hv[12],h13=hv[13],h14=hv[14],h15=hv[15],
            h16=hv[16],h17=hv[17],h18=hv[18],h19=hv[19],h20=hv[20],h21=hv[21],h22=hv[22],h23=hv[23],
            h24=hv[24],h25=hv[25],h26=hv[26],h27=hv[27],h28=hv[28],h29=hv[29],h30=hv[30],h31=hv[31];
        v2f A0={gcur,0.f}, A1={0.f,0.f}, A2={0.f,0.f}, A3={0.f,0.f};
        pkfma(A0,w00,h00); pkfma(A1,w01,h01); pkfma(A2,w02,h02); pkfma(A3,w03,h03);
        pkfma(A0,w04,h04); pkfma(A1,w05,h05); pkfma(A2,w06,h06); pkfma(A3,w07,h07);
        pkfma(A0,w08,h08); pkfma(A1,w09,h09); pkfma(A2,w10,h10); pkfma(A3,w11,h11);
        pkfma(A0,w12,h12); pkfma(A1,w13,h13); pkfma(A2,w14,h14); pkfma(A3,w15,h15);
        pkfma(A0,w16,h16); pkfma(A1,w17,h17); pkfma(A2,w18,h18); pkfma(A3,w19,h19);
        pkfma(A0,w20,h20); pkfma(A1,w21,h21); pkfma(A2,w22,h22); pkfma(A3,w23,h23);
        pkfma(A0,w24,h24); pkfma(A1,w25,h25); pkfma(A2,w26,h26); pkfma(A3,w27,h27);
        pkfma(A0,w28,h28); pkfma(A1,w29,h29); pkfma(A2,w30,h30); pkfma(A3,w31,h31);
        float* gs = gsum[step & 1];
        gs[gi] = ((A0.x+A0.y) + (A1.x+A1.y)) + ((A2.x+A2.y) + (A3.x+A3.y));
        __syncthreads();                           // the ONLY barrier per step
        float ig = gs[l], fg = gs[H+l], gg = gs[2*H+l], og = gs[3*H+l];
        c = fsig(fg)*c + fsig(ig)*ftanh(gg);       // all waves: identical update
        float hn = fsig(og)*ftanh(c);
        hs[l] = hn;                                // every wave writes full hs
        if (gi < H) hid[t*2*H + dir*H + gi] = hn;  // one wave publishes
        gcur = gnext;
    }
}

// ---------------- LSTM recurrence, H=32 T=64: single wave, NO barrier --------------
__global__ __launch_bounds__(64)
__attribute__((amdgpu_waves_per_eu(1, 1)))
void k_lstm_rec32(
        const float* __restrict__ gin_f, const float* __restrict__ wh_f,
        const float* __restrict__ gin_b, const float* __restrict__ wh_b,
        float* __restrict__ hid /* [T][64] */){
    const int H = 32, T = 64;
    int dir = blockIdx.x;
    const float* gin = dir ? gin_b : gin_f;
    const float* wh  = dir ? wh_b  : wh_f;
    int gi = threadIdx.x;                  // 0..63
    v2f wA[16], wB[16];
    {
        const v2f* rA = (const v2f*)(wh + (size_t)(     gi)*H);   // rows 0..63:  i|f
        const v2f* rB = (const v2f*)(wh + (size_t)(64 + gi)*H);   // rows 64..127: g|o
        #pragma unroll
        for (int k=0;k<16;k++){ wA[k]=rA[k]; wB[k]=rB[k]; }
    }
    __shared__ __align__(16) float hs[H];
    float c = 0.f;
    if (gi < H) hs[gi] = 0.f;
    __syncthreads();
    const float* gp = gin + gi;
    int ts0 = dir ? (T-1) : 0, ts1 = dir ? (T-2) : 1;
    float g0 = gp[ts0*128], g1 = gp[ts0*128 + 64];
    float n0 = gp[ts1*128], n1 = gp[ts1*128 + 64];
    bool lo = (gi < H);
    for (int step=0; step<T; step++){
        int t = dir ? (T-1-step) : step;
        float p0=0.f, p1=0.f;
        if (step+2 < T){
            int tp = dir ? (T-3-step) : (step+2);
            p0 = gp[tp*128]; p1 = gp[tp*128 + 64];
        }
        v2f aA = {g0, 0.f}, aB = {g1, 0.f};
        const v2f* hv = (const v2f*)hs;
        #pragma unroll
        for (int k=0;k<16;k++){
            v2f h2 = hv[k];
            pkfma(aA, wA[k], h2);
            pkfma(aB, wB[k], h2);
        }
        float sA = aA.x + aA.y;            // lane<32: i ; lane>=32: f
        float sB = aB.x + aB.y;            // lane<32: g ; lane>=32: o
        float pA = __shfl(sA, gi ^ 32);
        float pB = __shfl(sB, gi ^ 32);
        float i_ = lo ? sA : pA;
        float f_ = lo ? pA : sA;
        float g_ = lo ? sB : pB;
        float o_ = lo ? pB : sB;
        c = fsig(f_)*c + fsig(i_)*ftanh(g_);
        float hn = fsig(o_)*ftanh(c);
        if (lo){
            hid[t*2*H + dir*H + gi] = hn;
            hs[gi] = hn;                   // same wave: in-order LDS, no barrier
        }
        g0 = n0; g1 = n1; n0 = p0; n1 = p1;
    }
}

// ---------------- si=0: rebuild nh in place = [beat_span | meas_span | nh_sec] -----
__global__ void k_spans(float* __restrict__ nh, const float* __restrict__ bh,
                        const float* __restrict__ mh,
                        const int* __restrict__ bn, const int* __restrict__ mn){
    int n = blockIdx.x, s = threadIdx.x;           // 320 threads
    float v;
    if (s < 128)      v = bh[bn[n]*128 + s];
    else if (s < 192) v = mh[mn[n]*64 + (s-128)];
    else              v = nh[n*SS + s];            // own-thread read-then-write: safe
    nh[n*SS + s] = v;
}

// ---------------- si=1: spans + final output fused ---------------------------------
__global__ void k_spans_out(const float* __restrict__ bh, const float* __restrict__ mh,
                            const float* __restrict__ nh, const float* __restrict__ nh2,
                            const int* __restrict__ bn, const int* __restrict__ mn,
                            float* __restrict__ out){
    int n = blockIdx.x, s = threadIdx.x;           // 448 threads
    float v;
    if (s < 128)      v = bh[bn[n]*128 + s];
    else if (s < 192) v = mh[mn[n]*64 + (s-128)];
    else if (s < 320) v = nh[n*SS + s];
    else              v = nh2[n*SS + 192 + (s-320)];
    out[n*448 + s] = v;
}

// ===========================================================================
extern "C" void kernel_launch(void* const* d_in, const int* in_sizes, int n_in,
                              void* d_out, int out_size, void* d_ws, size_t ws_size,
                              hipStream_t stream) {
    const float* nodes    = (const float*)d_in[0];
    const float* adj      = (const float*)d_in[1];
    const int*   bn       = (const int*)  d_in[2];
    const int*   mn       = (const int*)  d_in[3];
    const float* fc_w     = (const float*)d_in[6];
    const float* fc_b     = (const float*)d_in[7];
    const float* g_wz[2]  = {(const float*)d_in[8],  (const float*)d_in[17]};
    const float* g_wr[2]  = {(const float*)d_in[9],  (const float*)d_in[18]};
    const float* g_wh[2]  = {(const float*)d_in[10], (const float*)d_in[19]};
    const float* g_uz[2]  = {(const float*)d_in[11], (const float*)d_in[20]};
    const float* g_ur[2]  = {(const float*)d_in[12], (const float*)d_in[21]};
    const float* g_uh[2]  = {(const float*)d_in[13], (const float*)d_in[22]};
    const float* g_bz[2]  = {(const float*)d_in[14], (const float*)d_in[23]};
    const float* g_br[2]  = {(const float*)d_in[15], (const float*)d_in[24]};
    const float* g_bh[2]  = {(const float*)d_in[16], (const float*)d_in[25]};
    const float* gb_w     = (const float*)d_in[26];
    const float* gb_b     = (const float*)d_in[27];
    const float* batt_w   = (const float*)d_in[28];
    const float* batt_b   = (const float*)d_in[29];
    const float* batt_c   = (const float*)d_in[30];
    const float* matt_w   = (const float*)d_in[31];
    const float* matt_b   = (const float*)d_in[32];
    const float* matt_c   = (const float*)d_in[33];
    const float* bwi_f    = (const float*)d_in[34];
    const float* bwh_f    = (const float*)d_in[35];
    const float* bb_f     = (const float*)d_in[36];
    const float* bwi_b    = (const float*)d_in[37];
    const float* bwh_b    = (const float*)d_in[38];
    const float* bb_b     = (const float*)d_in[39];
    const float* mwi_f    = (const float*)d_in[40];
    const float* mwh_f    = (const float*)d_in[41];
    const float* mb_f     = (const float*)d_in[42];
    const float* mwi_b    = (const float*)d_in[43];
    const float* mwh_b    = (const float*)d_in[44];
    const float* mb_b     = (const float*)d_in[45];
    float* out = (float*)d_out;

    // --- workspace layout (floats; ~27 MB) ---
    float* W_   = (float*)d_ws;
    float* nh   = W_;                       // 1024*320
    float* nh2  = nh   + 327680;            // 1024*320
    float* act  = nh2  + 327680;            // 10*1024*320
    float* part = act  + 3276800;           // 5*1024*384
    float* bgf  = part + 1966080;           // 256*256
    float* bgb  = bgf  + 65536;             // 256*256
    float* beat_hidden = bgb + 65536;       // 256*128
    float* mgf  = beat_hidden + 32768;      // 64*128
    float* mgb  = mgf  + 8192;              // 64*128
    float* meas_hidden = mgb + 8192;        // 64*64
    int*   cnt  = (int*)(meas_hidden + 4096);  // 10*1024
    int*   idx  = cnt + 10240;                  // 10*1024*64

    hipMemsetAsync(cnt, 0, EE*NN*sizeof(int), stream);
    k_csr_build<<<EE*NN, 256, 0, stream>>>(adj, cnt, idx);
    k_note_fc<<<NN, 128, 0, stream>>>(nodes, fc_w, fc_b, nh);

    for (int si = 0; si < 2; ++si){
        for (int it = 0; it < 2; ++it){
            k_gather_act<<<EE*NN, SS, 0, stream>>>(nh, cnt, idx, act);
            k_gate_gemm<<<dim3(32,3,5), 256, 0, stream>>>(act, g_wz[0], g_wr[0], g_wh[0], part);
            k_gru<<<NN/2, 128, 0, stream>>>(nh, part, g_uz[0], g_ur[0], g_uh[0],
                                            g_bz[0], g_br[0], g_bh[0]);
        }
        k_gb<<<NN/8, SS, 0, stream>>>(nh, gb_w, gb_b, nh2);
        for (int it = 0; it < 2; ++it){
            k_gather_act<<<EE*NN, SS, 0, stream>>>(nh2, cnt, idx, act);
            k_gate_gemm<<<dim3(32,3,5), 256, 0, stream>>>(act, g_wz[1], g_wr[1], g_wh[1], part);
            k_gru<<<NN/2, 128, 0, stream>>>(nh2, part, g_uz[1], g_ur[1], g_uh[1],
                                            g_bz[1], g_br[1], g_bh[1]);
        }
        k_batt_fused<<<NB, 256, 0, stream>>>(nh, nh2, batt_w, batt_b, batt_c,
                                             bwi_f, bb_f, bwi_b, bb_b, bgf, bgb);
        k_lstm_rec64<<<2, 256, 0, stream>>>(bgf, bwh_f, bgb, bwh_b, beat_hidden);
        k_matt_fused<<<NM, 128, 0, stream>>>(beat_hidden, matt_w, matt_b, matt_c,
                                             mwi_f, mb_f, mwi_b, mb_b, mgf, mgb);
        k_lstm_rec32<<<2, 64, 0, stream>>>(mgf, mwh_f, mgb, mwh_b, meas_hidden);
        if (si == 0)
            k_spans<<<NN, SS, 0, stream>>>(nh, beat_hidden, meas_hidden, bn, mn);
        else
            k_spans_out<<<NN, 448, 0, stream>>>(beat_hidden, meas_hidden, nh, nh2,
                                                bn, mn, out);
    }
}